// Round 9
// baseline (38683.557 us; speedup 1.0000x reference)
//
#include <hip/hip_runtime.h>
#include <math.h>

// Problem constants
#define Bq 8
#define Tt 128
#define Ee 384
#define Hh 768
#define Ll 9
#define GATE 1536   // 4*E

typedef float    f32x4 __attribute__((ext_vector_type(4)));
typedef unsigned u32x4 __attribute__((ext_vector_type(4)));

__device__ __forceinline__ float fast_sigmoid(float x) {
    return 1.f / (1.f + __expf(-x));
}
__device__ __forceinline__ float fast_tanh(float x) {
    return 1.f - 2.f / (__expf(2.f * x) + 1.f);
}

// ---------------------------------------------------------------------------
// Generic f32 GEMM (unchanged from R8)
// ---------------------------------------------------------------------------
#define BM 128
#define BN 128
#define BKk 16

__global__ __launch_bounds__(256) void k_gemm(
    const float* __restrict__ A, const float* __restrict__ Bw, float* __restrict__ C,
    int M, int N, int K,
    long sAz, long sBz, long sCz,
    const float* __restrict__ b1, const float* __restrict__ b2, long sbz,
    const float* __restrict__ bbn)
{
    int z = blockIdx.z;
    A += (long)z * sAz;
    Bw += (long)z * sBz;
    C += (long)z * sCz;
    const float* bb1 = b1 ? b1 + (long)z * sbz : nullptr;
    const float* bb2 = b2 ? b2 + (long)z * sbz : nullptr;

    int n0 = blockIdx.x * BN;
    int m0 = blockIdx.y * BM;
    int tid = threadIdx.x;

    __shared__ float As[BKk][BM];
    __shared__ float Bs[BKk][BN];

    int lr = tid >> 2;
    int lc = (tid & 3) * 4;
    int tx = tid & 15;
    int ty = tid >> 4;

    float acc[8][8];
#pragma unroll
    for (int i = 0; i < 8; ++i)
#pragma unroll
        for (int j = 0; j < 8; ++j) acc[i][j] = 0.f;

    for (int k0 = 0; k0 < K; k0 += BKk) {
        float4 a0 = *(const float4*)&A[(long)(m0 + lr) * K + k0 + lc];
        float4 a1 = *(const float4*)&A[(long)(m0 + lr + 64) * K + k0 + lc];
        float4 w0 = *(const float4*)&Bw[(long)(n0 + lr) * K + k0 + lc];
        float4 w1 = *(const float4*)&Bw[(long)(n0 + lr + 64) * K + k0 + lc];
        __syncthreads();
        As[lc + 0][lr] = a0.x; As[lc + 1][lr] = a0.y; As[lc + 2][lr] = a0.z; As[lc + 3][lr] = a0.w;
        As[lc + 0][lr + 64] = a1.x; As[lc + 1][lr + 64] = a1.y; As[lc + 2][lr + 64] = a1.z; As[lc + 3][lr + 64] = a1.w;
        Bs[lc + 0][lr] = w0.x; Bs[lc + 1][lr] = w0.y; Bs[lc + 2][lr] = w0.z; Bs[lc + 3][lr] = w0.w;
        Bs[lc + 0][lr + 64] = w1.x; Bs[lc + 1][lr + 64] = w1.y; Bs[lc + 2][lr + 64] = w1.z; Bs[lc + 3][lr + 64] = w1.w;
        __syncthreads();
#pragma unroll
        for (int kk = 0; kk < BKk; ++kk) {
            float av[8], bv[8];
            *(float4*)&av[0] = *(float4*)&As[kk][ty * 8];
            *(float4*)&av[4] = *(float4*)&As[kk][ty * 8 + 4];
            *(float4*)&bv[0] = *(float4*)&Bs[kk][tx * 8];
            *(float4*)&bv[4] = *(float4*)&Bs[kk][tx * 8 + 4];
#pragma unroll
            for (int i = 0; i < 8; ++i)
#pragma unroll
                for (int j = 0; j < 8; ++j)
                    acc[i][j] = fmaf(av[i], bv[j], acc[i][j]);
        }
    }

#pragma unroll
    for (int i = 0; i < 8; ++i) {
        long m = m0 + ty * 8 + i;
#pragma unroll
        for (int j = 0; j < 8; ++j) {
            int n = n0 + tx * 8 + j;
            float val = acc[i][j];
            if (bb1) val += bb1[n];
            if (bb2) val += bb2[n];
            if (bbn) val += bbn[(m >> 7) * (long)N + n];
            C[m * N + n] = val;
        }
    }
}

// ---------------------------------------------------------------------------
// sc0 (L1-bypass, L2-cached) load/store helpers + agent fallback.
// ---------------------------------------------------------------------------
__device__ __forceinline__ f32x4 ld_sc0_f4(const float* p) {
    f32x4 r;
    asm volatile("global_load_dwordx4 %0, %1, off sc0\n\ts_waitcnt vmcnt(0)"
                 : "=&v"(r) : "v"(p) : "memory");
    return r;
}
__device__ __forceinline__ f32x4 ld_agent_f4(const float* p) {
    const unsigned long long* q = (const unsigned long long*)p;
    unsigned long long lo = __hip_atomic_load(q,     __ATOMIC_RELAXED, __HIP_MEMORY_SCOPE_AGENT);
    unsigned long long hi = __hip_atomic_load(q + 1, __ATOMIC_RELAXED, __HIP_MEMORY_SCOPE_AGENT);
    float2 a = __builtin_bit_cast(float2, lo);
    float2 b = __builtin_bit_cast(float2, hi);
    f32x4 r; r.x = a.x; r.y = a.y; r.z = b.x; r.w = b.y;
    return r;
}
__device__ __forceinline__ bool f4_has_sent(f32x4 v) {
    u32x4 u = __builtin_bit_cast(u32x4, v);
    return (u.x == 0xFFFFFFFFu) | (u.y == 0xFFFFFFFFu) |
           (u.z == 0xFFFFFFFFu) | (u.w == 0xFFFFFFFFu);
}
__device__ __forceinline__ f32x4 resolve_word(f32x4 v, const float* p, bool& use_local) {
    if (!f4_has_sent(v)) return v;
    if (use_local) {
        int spins = 0;
        for (;;) {
            v = ld_sc0_f4(p);
            if (!f4_has_sent(v)) return v;
            if (++spins > 4000) { use_local = false; break; }  // permanent fallback
        }
    }
    while (f4_has_sent(v)) v = ld_agent_f4(p);
    return v;
}

// ---------------------------------------------------------------------------
// LSTM recurrence — XCD-colocated groups exchanging h through the shared
// per-XCD L2 (sc0 ops), with agent-scope (L3) dual-store + bounded-spin
// fallback so correctness never depends on placement or cache policy.
//
// 256 blocks launched. Each block reads its physical XCC_ID and tickets into
// a per-XCD counter; ranks 0..15 of each XCD form a complete 16-slice group
// handling dir = xcd&1 (4 redundant groups per direction; h values are a pure
// function of the inputs so duplicates write identical values). Others exit.
//
// Producer: h -> global_store sc0 (own L2, fast path) + agent store (L3).
// Consumer: batch sc0 dwordx4 loads -> sentinel check -> bounded sc0 repoll
// -> permanent agent fallback. Yout pre-filled with 0xFFFFFFFF (NaN).
// ---------------------------------------------------------------------------
__global__ __launch_bounds__(256, 1) void k_lstm(
    const float* __restrict__ G, const float* __restrict__ Whh, float* Yout,
    unsigned* cnt)
{
    unsigned xcd;
    asm volatile("s_getreg_b32 %0, hwreg(HW_REG_XCC_ID)" : "=s"(xcd));
    xcd &= 7u;

    __shared__ unsigned sh_rank;
    if (threadIdx.x == 0)
        sh_rank = __hip_atomic_fetch_add(&cnt[xcd * 32], 1u,
                                         __ATOMIC_RELAXED, __HIP_MEMORY_SCOPE_AGENT);
    __syncthreads();
    unsigned rank = sh_rank;
    if (rank >= 16u) return;               // non-worker

    int d = (int)(xcd & 1u);               // direction
    int s = (int)rank;                     // slice 0..15
    int tid = threadIdx.x;
    int kq = tid >> 5;                     // 0..7  (k-range of 48)
    int rg = tid & 31;                     // 0..31 (3 rows each)
    int kq48 = kq * 48;

    __shared__ float hl[8 * 384];          // h_prev for all batches of this dir
    __shared__ float part[8 * 776];        // partials: [kq][b(stride 97)][row 0..95]

    // Load W slice into registers
    float W_[3][48];
    const float* Wd = Whh + (long)d * GATE * Ee;
#pragma unroll
    for (int r = 0; r < 3; ++r) {
        int rl = rg * 3 + r;
        int g = rl / 24, rr = rl % 24;
        const float* src = Wd + (long)(g * Ee + s * 24 + rr) * Ee + kq48;
#pragma unroll
        for (int k4 = 0; k4 < 12; ++k4) {
            float4 w = *(const float4*)&src[k4 * 4];
            W_[r][k4 * 4 + 0] = w.x;
            W_[r][k4 * 4 + 1] = w.y;
            W_[r][k4 * 4 + 2] = w.z;
            W_[r][k4 * 4 + 3] = w.w;
        }
    }

    float cst = 0.f;
    int ub = tid / 24, ur = tid - ub * 24;
    bool upd = tid < 192;
    bool use_local = true;

    // G prefetch (one timestep ahead)
    float gpre[4];
    const float* gbase = G + ((long)d * 1024 + ub * Tt) * GATE + s * 24 + ur;
    {
        int tt0 = d ? 127 : 0;
        if (upd) {
#pragma unroll
            for (int g = 0; g < 4; ++g) gpre[g] = gbase[(long)tt0 * GATE + g * Ee];
        }
    }

    f32x4* hl4 = (f32x4*)hl;

    for (int it = 0; it < 128; ++it) {
        int tt = d ? (127 - it) : it;
        int tp = d ? (tt + 1) : (tt - 1);

        if (it == 0) {
            f32x4 z4 = (f32x4)0.f;
#pragma unroll
            for (int ii = 0; ii < 3; ++ii) hl4[tid + 256 * ii] = z4;
        } else {
            const float* p[3];
#pragma unroll
            for (int ii = 0; ii < 3; ++ii) {
                int i4 = tid + 256 * ii;       // 0..767
                int b = i4 / 96, k4 = i4 - b * 96;
                p[ii] = &Yout[((long)(b * Tt + tp)) * Hh + d * Ee + k4 * 4];
            }
            f32x4 v0, v1, v2;
            if (use_local) {
                asm volatile(
                    "global_load_dwordx4 %0, %3, off sc0\n\t"
                    "global_load_dwordx4 %1, %4, off sc0\n\t"
                    "global_load_dwordx4 %2, %5, off sc0\n\t"
                    "s_waitcnt vmcnt(0)"
                    : "=&v"(v0), "=&v"(v1), "=&v"(v2)
                    : "v"(p[0]), "v"(p[1]), "v"(p[2])
                    : "memory");
            } else {
                v0 = ld_agent_f4(p[0]);
                v1 = ld_agent_f4(p[1]);
                v2 = ld_agent_f4(p[2]);
            }
            v0 = resolve_word(v0, p[0], use_local);
            v1 = resolve_word(v1, p[1], use_local);
            v2 = resolve_word(v2, p[2], use_local);
            hl4[tid]       = v0;
            hl4[tid + 256] = v1;
            hl4[tid + 512] = v2;
        }
        __syncthreads();

        float acc[8][3];
#pragma unroll
        for (int b = 0; b < 8; ++b)
#pragma unroll
            for (int r = 0; r < 3; ++r) acc[b][r] = 0.f;

#pragma unroll
        for (int k4 = 0; k4 < 12; ++k4) {
#pragma unroll
            for (int b = 0; b < 8; ++b) {
                float4 hv = *(const float4*)&hl[b * 384 + kq48 + k4 * 4];
#pragma unroll
                for (int r = 0; r < 3; ++r) {
                    acc[b][r] = fmaf(W_[r][k4 * 4 + 0], hv.x, acc[b][r]);
                    acc[b][r] = fmaf(W_[r][k4 * 4 + 1], hv.y, acc[b][r]);
                    acc[b][r] = fmaf(W_[r][k4 * 4 + 2], hv.z, acc[b][r]);
                    acc[b][r] = fmaf(W_[r][k4 * 4 + 3], hv.w, acc[b][r]);
                }
            }
        }

#pragma unroll
        for (int b = 0; b < 8; ++b)
#pragma unroll
            for (int r = 0; r < 3; ++r)
                part[kq * 776 + b * 97 + rg * 3 + r] = acc[b][r];
        __syncthreads();

        if (upd) {
            float gt[4];
#pragma unroll
            for (int g = 0; g < 4; ++g) {
                int rl = g * 24 + ur;
                float sum = gpre[g];
#pragma unroll
                for (int q = 0; q < 8; ++q) sum += part[q * 776 + ub * 97 + rl];
                gt[g] = sum;
            }
            float ig = fast_sigmoid(gt[0]);
            float fg = fast_sigmoid(gt[1]);
            float gg = fast_tanh(gt[2]);
            float og = fast_sigmoid(gt[3]);
            cst = fg * cst + ig * gg;
            float h = og * fast_tanh(cst);
            float* dst = &Yout[((long)(ub * Tt + tt)) * Hh + d * Ee + s * 24 + ur];
            // dual store: local L2 copy (fast path) + L3 copy (fallback path)
            asm volatile("global_store_dword %0, %1, off sc0"
                         :: "v"(dst), "v"(h) : "memory");
            __hip_atomic_store(dst, h, __ATOMIC_RELAXED, __HIP_MEMORY_SCOPE_AGENT);
            if (it != 127) {
                int ttn = d ? (tt - 1) : (tt + 1);
#pragma unroll
                for (int g = 0; g < 4; ++g) gpre[g] = gbase[(long)ttn * GATE + g * Ee];
            }
        }
    }
}

// ---------------------------------------------------------------------------
// Sentinel pre-fill
// ---------------------------------------------------------------------------
__global__ void k_fill_sent(float* __restrict__ p, int n4)
{
    int i = blockIdx.x * 256 + threadIdx.x;
    if (i < n4) {
        unsigned u = 0xFFFFFFFFu;
        float f = __builtin_bit_cast(float, u);
        ((float4*)p)[i] = make_float4(f, f, f, f);
    }
}

// ---------------------------------------------------------------------------
// p_term (unchanged)
// ---------------------------------------------------------------------------
__global__ __launch_bounds__(256) void k_pterm(
    const float* __restrict__ hs, const int* __restrict__ qids,
    const float* __restrict__ Wp, float* __restrict__ pterm)
{
    int b = blockIdx.y;
    int chunk = blockIdx.x;
    int tid = threadIdx.x;
    int qid = qids[b];
    __shared__ float hp[Hh];
    for (int i = tid; i < Hh; i += 256) hp[i] = hs[((long)(b * Tt + qid)) * Hh + i];
    __syncthreads();
    int w = tid >> 6, lane = tid & 63;
#pragma unroll
    for (int r = 0; r < 8; ++r) {
        int n = chunk * 32 + w * 8 + r;
        const float* wrow = &Wp[(long)n * Hh];
        float p = 0.f;
#pragma unroll
        for (int k0 = 0; k0 < 3; ++k0) {
            int k = lane * 4 + k0 * 256;
            float4 wv = *(const float4*)&wrow[k];
            float4 hv = *(const float4*)&hp[k];
            p += wv.x * hv.x + wv.y * hv.y + wv.z * hv.z + wv.w * hv.w;
        }
#pragma unroll
        for (int o = 32; o; o >>= 1) p += __shfl_down(p, o);
        if (lane == 0) pterm[b * Hh + n] = p;
    }
}

// ---------------------------------------------------------------------------
// Fused attention (unchanged)
// ---------------------------------------------------------------------------
__global__ __launch_bounds__(256) void k_attn(
    const float* __restrict__ hs, const float* __restrict__ A1, const float* __restrict__ A2,
    const float* __restrict__ v, const float* __restrict__ Wclf,
    float* __restrict__ a_mat, float* __restrict__ logits)
{
    int b = blockIdx.x >> 7, t = blockIdx.x & 127;
    int tid = threadIdx.x;
    long bt = (long)(b * Tt + t);

    __shared__ float a2r[Hh], vr[Hh], hsr[Hh], crow[Hh];
    __shared__ float sc[128], tmp[256], red2[2];

    for (int i = tid; i < Hh; i += 256) {
        a2r[i] = A2[bt * Hh + i];
        vr[i] = v[i];
        hsr[i] = hs[bt * Hh + i];
    }
    __syncthreads();

    {
        int sid = tid >> 1, half = tid & 1;
        float p = 0.f;
        const float* A1r = &A1[((long)(b * Tt + sid)) * Hh + half * 384];
        const float* a2h = &a2r[half * 384];
        const float* vh = &vr[half * 384];
        for (int k = 0; k < 384; k += 4) {
            float4 z = *(const float4*)&A1r[k];
            p += vh[k + 0] * fast_tanh(z.x + a2h[k + 0]);
            p += vh[k + 1] * fast_tanh(z.y + a2h[k + 1]);
            p += vh[k + 2] * fast_tanh(z.z + a2h[k + 2]);
            p += vh[k + 3] * fast_tanh(z.w + a2h[k + 3]);
        }
        tmp[tid] = p;
    }
    __syncthreads();
    if (tid < 128) sc[tid] = tmp[2 * tid] + tmp[2 * tid + 1];
    __syncthreads();

    if (tid < 64) {
        float m = fmaxf(sc[tid], sc[tid + 64]);
#pragma unroll
        for (int o = 32; o; o >>= 1) m = fmaxf(m, __shfl_down(m, o));
        if (tid == 0) red2[0] = m;
    }
    __syncthreads();
    float mx = red2[0];
    if (tid < 128) sc[tid] = __expf(sc[tid] - mx);
    __syncthreads();
    if (tid < 64) {
        float sm = sc[tid] + sc[tid + 64];
#pragma unroll
        for (int o = 32; o; o >>= 1) sm += __shfl_down(sm, o);
        if (tid == 0) red2[1] = sm;
    }
    __syncthreads();
    float inv = 1.f / red2[1];
    if (tid < 128) {
        sc[tid] *= inv;
        a_mat[bt * 128 + tid] = sc[tid];
    }
    __syncthreads();

    float c0 = 0.f, c1 = 0.f, c2 = 0.f;
    for (int s2 = 0; s2 < 128; ++s2) {
        float as = sc[s2];
        const float* hrow = &hs[((long)(b * Tt + s2)) * Hh];
        c0 = fmaf(as, hrow[tid], c0);
        c1 = fmaf(as, hrow[tid + 256], c1);
        c2 = fmaf(as, hrow[tid + 512], c2);
    }
    crow[tid] = c0; crow[tid + 256] = c1; crow[tid + 512] = c2;
    __syncthreads();

    for (int l = 0; l < Ll; ++l) {
        float p = 0.f;
        for (int h = tid; h < 2 * Hh; h += 256) {
            float u = (h < Hh) ? hsr[h] : crow[h - Hh];
            p = fmaf(u, Wclf[l * 2 * Hh + h], p);
        }
#pragma unroll
        for (int o = 32; o; o >>= 1) p += __shfl_down(p, o);
        if ((tid & 63) == 0) tmp[tid >> 6] = p;
        __syncthreads();
        if (tid == 0) logits[bt * Ll + l] = tmp[0] + tmp[1] + tmp[2] + tmp[3];
        __syncthreads();
    }
}

// ---------------------------------------------------------------------------
// a_t normalization (unchanged)
// ---------------------------------------------------------------------------
__global__ void k_norm(const float* __restrict__ a_mat, float* __restrict__ a_t)
{
    int b = blockIdx.x;
    int s = threadIdx.x;
    float sum = 0.f;
    for (int t = 0; t < Tt; ++t) sum += a_mat[((long)(b * Tt + t)) * 128 + s];
    __shared__ float pool[128];
    __shared__ float tot;
    pool[s] = sum;
    __syncthreads();
    if (s < 64) {
        float v2 = pool[s] + pool[s + 64];
#pragma unroll
        for (int o = 32; o; o >>= 1) v2 += __shfl_down(v2, o);
        if (s == 0) tot = v2;
    }
    __syncthreads();
    float tv = tot;
    a_t[b * 128 + s] = (tv != 0.f) ? pool[s] / tv : 0.f;
}

// ---------------------------------------------------------------------------
// Viterbi (unchanged)
// ---------------------------------------------------------------------------
__global__ void k_viterbi(const float* __restrict__ logits, const float* __restrict__ trans,
                          const float* __restrict__ start, const float* __restrict__ endw,
                          float* __restrict__ out)
{
    __shared__ float sc[2][72];
    __shared__ unsigned char ptrs[127][72];
    __shared__ unsigned char tags[8][128];
    int tid = threadIdx.x;
    int b = tid / 9, j = tid % 9;
    bool act = tid < 72;
    if (act) sc[0][b * 9 + j] = start[j] + logits[(b * Tt + 0) * Ll + j];
    __syncthreads();
    for (int t = 1; t < Tt; ++t) {
        int cur = t & 1, prv = cur ^ 1;
        if (act) {
            float best = -1e30f; int bi = 0;
#pragma unroll
            for (int i = 0; i < 9; ++i) {
                float vv = sc[prv][b * 9 + i] + trans[i * 9 + j];
                if (vv > best) { best = vv; bi = i; }
            }
            sc[cur][b * 9 + j] = best + logits[(b * Tt + t) * Ll + j];
            ptrs[t - 1][b * 9 + j] = (unsigned char)bi;
        }
        __syncthreads();
    }
    if (act && j == 0) {
        float best = -1e30f; int bj = 0;
#pragma unroll
        for (int jj = 0; jj < 9; ++jj) {
            float vv = sc[1][b * 9 + jj] + endw[jj];
            if (vv > best) { best = vv; bj = jj; }
        }
        int tg = bj;
        tags[b][127] = (unsigned char)tg;
        for (int t = 127; t >= 1; --t) {
            tg = ptrs[t - 1][b * 9 + tg];
            tags[b][t - 1] = (unsigned char)tg;
        }
    }
    __syncthreads();
    for (int i = tid; i < Bq * Tt * Ll; i += blockDim.x) {
        int l = i % 9;
        int btx = i / 9;
        int tt2 = btx % Tt;
        int bb = btx / Tt;
        out[i] = (tags[bb][tt2] == l) ? 10.f : -1.f;
    }
}

// ---------------------------------------------------------------------------
extern "C" void kernel_launch(void* const* d_in, const int* in_sizes, int n_in,
                              void* d_out, int out_size, void* d_ws, size_t ws_size,
                              hipStream_t stream)
{
    const float* embeds   = (const float*)d_in[0];
    const int*   qids     = (const int*)d_in[1];
    const float* w_ih_l0  = (const float*)d_in[2];
    const float* w_ih_rest= (const float*)d_in[3];
    const float* w_hh     = (const float*)d_in[4];
    const float* b_ih     = (const float*)d_in[5];
    const float* b_hh     = (const float*)d_in[6];
    const float* W_H      = (const float*)d_in[7];
    const float* W_p      = (const float*)d_in[8];
    const float* W_h      = (const float*)d_in[9];
    const float* vvec     = (const float*)d_in[10];
    const float* W_clf    = (const float*)d_in[11];
    const float* trans    = (const float*)d_in[12];
    const float* cstart   = (const float*)d_in[13];
    const float* cend     = (const float*)d_in[14];

    float* out = (float*)d_out;
    float* vit_out = out;                          // 8*128*9   = 9216
    float* hs      = out + 9216;                   // 8*128*768 = 786432
    float* a_t     = out + 9216 + 786432;          // 8*128     = 1024

    float* ws = (float*)d_ws;
    float* G      = ws;                  // 3145728 floats
    float* Y0     = ws + 3145728;        // 786432
    float* Y1     = Y0 + 786432;         // 786432
    unsigned* cnt = (unsigned*)(ws + 3145728 + 2 * 786432);  // 3 layers x 256 u32
    float* A1     = ws;                  // reuses G (dead after last lstm)
    float* A2     = A1 + 786432;
    float* pterm  = A2 + 786432;
    float* a_mat  = pterm + 6144;
    float* logits = a_mat + 131072;

    dim3 blk(256);
    const int n4 = 786432 / 4;
    const int fillgrid = (n4 + 255) / 256;

    // Reset ticket counters + sentinel pre-fill (deterministic, capture-safe).
    (void)hipMemsetAsync(cnt, 0, 3 * 256 * sizeof(unsigned), stream);
    k_fill_sent<<<dim3(fillgrid), blk, 0, stream>>>(Y0, n4);
    k_fill_sent<<<dim3(fillgrid), blk, 0, stream>>>(Y1, n4);
    k_fill_sent<<<dim3(fillgrid), blk, 0, stream>>>(hs, n4);

    // ---- Layer 0 ----
    k_gemm<<<dim3(GATE / BN, 1024 / BM, 2), blk, 0, stream>>>(
        embeds, w_ih_l0, G, 1024, GATE, Ee,
        0L, (long)GATE * Ee, (long)1024 * GATE,
        b_ih, b_hh, (long)GATE, nullptr);
    k_lstm<<<dim3(256), blk, 0, stream>>>(G, w_hh, Y0, cnt);

    // ---- Layer 1 ----
    k_gemm<<<dim3(GATE / BN, 1024 / BM, 2), blk, 0, stream>>>(
        Y0, w_ih_rest, G, 1024, GATE, Hh,
        0L, (long)GATE * Hh, (long)1024 * GATE,
        b_ih + 2 * GATE, b_hh + 2 * GATE, (long)GATE, nullptr);
    k_lstm<<<dim3(256), blk, 0, stream>>>(G, w_hh + (long)2 * GATE * Ee, Y1, cnt + 256);

    // ---- Layer 2 ----
    k_gemm<<<dim3(GATE / BN, 1024 / BM, 2), blk, 0, stream>>>(
        Y1, w_ih_rest + (long)2 * GATE * Hh, G, 1024, GATE, Hh,
        0L, (long)GATE * Hh, (long)1024 * GATE,
        b_ih + 4 * GATE, b_hh + 4 * GATE, (long)GATE, nullptr);
    k_lstm<<<dim3(256), blk, 0, stream>>>(G, w_hh + (long)4 * GATE * Ee, hs, cnt + 512);

    // ---- Attention precompute ----
    k_pterm<<<dim3(24, 8), blk, 0, stream>>>(hs, qids, W_p, pterm);
    k_gemm<<<dim3(Hh / BN, 1024 / BM, 1), blk, 0, stream>>>(
        hs, W_H, A1, 1024, Hh, Hh, 0L, 0L, 0L, nullptr, nullptr, 0L, nullptr);
    k_gemm<<<dim3(Hh / BN, 1024 / BM, 1), blk, 0, stream>>>(
        hs, W_h, A2, 1024, Hh, Hh, 0L, 0L, 0L, nullptr, nullptr, 0L, pterm);

    // ---- Fused attention + logits ----
    k_attn<<<dim3(1024), blk, 0, stream>>>(hs, A1, A2, vvec, W_clf, a_mat, logits);

    // ---- Pooled attention norm -> a_t ----
    k_norm<<<dim3(8), dim3(128), 0, stream>>>(a_mat, a_t);

    // ---- Viterbi -> vit_logits ----
    k_viterbi<<<dim3(1), dim3(128), 0, stream>>>(logits, trans, cstart, cend, vit_out);
}

// Round 10
// 2293.336 us; speedup vs baseline: 16.8678x; 16.8678x over previous
//
#include <hip/hip_runtime.h>
#include <math.h>

// Problem constants
#define Bq 8
#define Tt 128
#define Ee 384
#define Hh 768
#define Ll 9
#define GATE 1536   // 4*E

__device__ __forceinline__ float fast_sigmoid(float x) {
    return 1.f / (1.f + __expf(-x));
}
__device__ __forceinline__ float fast_tanh(float x) {
    return 1.f - 2.f / (__expf(2.f * x) + 1.f);
}

// ---------------------------------------------------------------------------
// Generic f32 GEMM (unchanged, known-good)
// ---------------------------------------------------------------------------
#define BM 128
#define BN 128
#define BKk 16

__global__ __launch_bounds__(256) void k_gemm(
    const float* __restrict__ A, const float* __restrict__ Bw, float* __restrict__ C,
    int M, int N, int K,
    long sAz, long sBz, long sCz,
    const float* __restrict__ b1, const float* __restrict__ b2, long sbz,
    const float* __restrict__ bbn)
{
    int z = blockIdx.z;
    A += (long)z * sAz;
    Bw += (long)z * sBz;
    C += (long)z * sCz;
    const float* bb1 = b1 ? b1 + (long)z * sbz : nullptr;
    const float* bb2 = b2 ? b2 + (long)z * sbz : nullptr;

    int n0 = blockIdx.x * BN;
    int m0 = blockIdx.y * BM;
    int tid = threadIdx.x;

    __shared__ float As[BKk][BM];
    __shared__ float Bs[BKk][BN];

    int lr = tid >> 2;
    int lc = (tid & 3) * 4;
    int tx = tid & 15;
    int ty = tid >> 4;

    float acc[8][8];
#pragma unroll
    for (int i = 0; i < 8; ++i)
#pragma unroll
        for (int j = 0; j < 8; ++j) acc[i][j] = 0.f;

    for (int k0 = 0; k0 < K; k0 += BKk) {
        float4 a0 = *(const float4*)&A[(long)(m0 + lr) * K + k0 + lc];
        float4 a1 = *(const float4*)&A[(long)(m0 + lr + 64) * K + k0 + lc];
        float4 w0 = *(const float4*)&Bw[(long)(n0 + lr) * K + k0 + lc];
        float4 w1 = *(const float4*)&Bw[(long)(n0 + lr + 64) * K + k0 + lc];
        __syncthreads();
        As[lc + 0][lr] = a0.x; As[lc + 1][lr] = a0.y; As[lc + 2][lr] = a0.z; As[lc + 3][lr] = a0.w;
        As[lc + 0][lr + 64] = a1.x; As[lc + 1][lr + 64] = a1.y; As[lc + 2][lr + 64] = a1.z; As[lc + 3][lr + 64] = a1.w;
        Bs[lc + 0][lr] = w0.x; Bs[lc + 1][lr] = w0.y; Bs[lc + 2][lr] = w0.z; Bs[lc + 3][lr] = w0.w;
        Bs[lc + 0][lr + 64] = w1.x; Bs[lc + 1][lr + 64] = w1.y; Bs[lc + 2][lr + 64] = w1.z; Bs[lc + 3][lr + 64] = w1.w;
        __syncthreads();
#pragma unroll
        for (int kk = 0; kk < BKk; ++kk) {
            float av[8], bv[8];
            *(float4*)&av[0] = *(float4*)&As[kk][ty * 8];
            *(float4*)&av[4] = *(float4*)&As[kk][ty * 8 + 4];
            *(float4*)&bv[0] = *(float4*)&Bs[kk][tx * 8];
            *(float4*)&bv[4] = *(float4*)&Bs[kk][tx * 8 + 4];
#pragma unroll
            for (int i = 0; i < 8; ++i)
#pragma unroll
                for (int j = 0; j < 8; ++j)
                    acc[i][j] = fmaf(av[i], bv[j], acc[i][j]);
        }
    }

#pragma unroll
    for (int i = 0; i < 8; ++i) {
        long m = m0 + ty * 8 + i;
#pragma unroll
        for (int j = 0; j < 8; ++j) {
            int n = n0 + tx * 8 + j;
            float val = acc[i][j];
            if (bb1) val += bb1[n];
            if (bb2) val += bb2[n];
            if (bbn) val += bbn[(m >> 7) * (long)N + n];
            C[m * N + n] = val;
        }
    }
}

// ---------------------------------------------------------------------------
// LSTM recurrence, sentinel-dataflow (R8 protocol) with FINE slicing so the
// per-thread W slice (72 floats) is register-resident (R5-R9 ran at
// VGPR_Count=136 < the 144-float W slice -> scratch reloads on the critical
// path each step).
// 64 blocks: d = bid>>5, slice s = bid&31 owns h-rows s*12..s*12+11
// (48 gate rows). Thread (kq=tid>>4: 24-k range, rg=tid&15: 3 gate rows).
// Yout pre-filled with 0xFFFFFFFF (NaN); h always finite. Writers fire
// agent-scope relaxed stores; readers parallel-issue all 6 h-words then
// verify, re-polling only missing words.
// ---------------------------------------------------------------------------
__device__ __forceinline__ bool has_sent(unsigned long long v) {
    return ((unsigned)v == 0xFFFFFFFFu) || ((unsigned)(v >> 32) == 0xFFFFFFFFu);
}

__global__ __launch_bounds__(256, 1) void k_lstm(
    const float* __restrict__ G, const float* __restrict__ Whh, float* Yout)
{
    int bid = blockIdx.x;
    int d = bid >> 5;           // direction
    int s = bid & 31;           // slice: h-rows s*12..s*12+11
    int tid = threadIdx.x;
    int kq = tid >> 4;          // 0..15 (k-range of 24)
    int rg = tid & 15;          // 0..15 (3 gate-rows each)
    int kq24 = kq * 24;

    __shared__ float hl[8 * 384];       // h_prev for all batches of this dir
    __shared__ float part[16 * 392];    // [kq][b(stride 49)][rl 0..47]

    // W slice: 3 gate rows x 24 k = 72 floats (register-resident)
    float W_[3][24];
    const float* Wd = Whh + (long)d * GATE * Ee;
#pragma unroll
    for (int r = 0; r < 3; ++r) {
        int rl = rg * 3 + r;            // 0..47
        int g = rl / 12, rr = rl % 12;
        const float* src = Wd + (long)(g * Ee + s * 12 + rr) * Ee + kq24;
#pragma unroll
        for (int k4 = 0; k4 < 6; ++k4) {
            float4 w = *(const float4*)&src[k4 * 4];
            W_[r][k4 * 4 + 0] = w.x;
            W_[r][k4 * 4 + 1] = w.y;
            W_[r][k4 * 4 + 2] = w.z;
            W_[r][k4 * 4 + 3] = w.w;
        }
    }

    float cst = 0.f;                    // cell state for update thread
    bool upd = tid < 96;
    int ub = upd ? (tid / 12) : 0;      // batch
    int ur = upd ? (tid - ub * 12) : 0; // h-row within slice

    // G prefetch (one timestep ahead)
    float gpre[4];
    const float* gbase = G + ((long)d * 1024 + ub * Tt) * GATE + s * 12 + ur;
    {
        int tt0 = d ? 127 : 0;
        if (upd) {
#pragma unroll
            for (int g = 0; g < 4; ++g) gpre[g] = gbase[(long)tt0 * GATE + g * Ee];
        }
    }

    float4* hl4 = (float4*)hl;

    for (int it = 0; it < 128; ++it) {
        int tt = d ? (127 - it) : it;
        int tp = d ? (tt + 1) : (tt - 1);

        // stage h_{prev}: parallel-issue all 6 words, then verify
        if (it == 0) {
            float4 z4 = make_float4(0.f, 0.f, 0.f, 0.f);
#pragma unroll
            for (int ii = 0; ii < 3; ++ii) hl4[tid + 256 * ii] = z4;
        } else {
            const unsigned long long* sp[6];
            unsigned long long v[6];
#pragma unroll
            for (int ii = 0; ii < 3; ++ii) {
                int i4 = tid + 256 * ii;       // 0..767
                int b = i4 / 96, k4 = i4 - b * 96;
                const unsigned long long* base = (const unsigned long long*)
                    &Yout[((long)(b * Tt + tp)) * Hh + d * Ee + k4 * 4];
                sp[2 * ii] = base;
                sp[2 * ii + 1] = base + 1;
            }
#pragma unroll
            for (int j = 0; j < 6; ++j)
                v[j] = __hip_atomic_load(sp[j], __ATOMIC_RELAXED, __HIP_MEMORY_SCOPE_AGENT);
#pragma unroll
            for (int j = 0; j < 6; ++j)
                while (has_sent(v[j]))
                    v[j] = __hip_atomic_load(sp[j], __ATOMIC_RELAXED, __HIP_MEMORY_SCOPE_AGENT);
#pragma unroll
            for (int ii = 0; ii < 3; ++ii) {
                int i4 = tid + 256 * ii;
                float2 flo = __builtin_bit_cast(float2, v[2 * ii]);
                float2 fhi = __builtin_bit_cast(float2, v[2 * ii + 1]);
                hl4[i4] = make_float4(flo.x, flo.y, fhi.x, fhi.y);
            }
        }
        __syncthreads();

        float acc[8][3];
#pragma unroll
        for (int b = 0; b < 8; ++b)
#pragma unroll
            for (int r = 0; r < 3; ++r) acc[b][r] = 0.f;

#pragma unroll
        for (int k4 = 0; k4 < 6; ++k4) {
#pragma unroll
            for (int b = 0; b < 8; ++b) {
                float4 hv = *(const float4*)&hl[b * 384 + kq24 + k4 * 4];
#pragma unroll
                for (int r = 0; r < 3; ++r) {
                    acc[b][r] = fmaf(W_[r][k4 * 4 + 0], hv.x, acc[b][r]);
                    acc[b][r] = fmaf(W_[r][k4 * 4 + 1], hv.y, acc[b][r]);
                    acc[b][r] = fmaf(W_[r][k4 * 4 + 2], hv.z, acc[b][r]);
                    acc[b][r] = fmaf(W_[r][k4 * 4 + 3], hv.w, acc[b][r]);
                }
            }
        }

        // write partials
#pragma unroll
        for (int b = 0; b < 8; ++b)
#pragma unroll
            for (int r = 0; r < 3; ++r)
                part[kq * 392 + b * 49 + rg * 3 + r] = acc[b][r];
        __syncthreads();

        if (upd) {
            float gt[4];
#pragma unroll
            for (int g = 0; g < 4; ++g) {
                int rl = g * 12 + ur;
                float sum = gpre[g];
#pragma unroll
                for (int q = 0; q < 16; ++q) sum += part[q * 392 + ub * 49 + rl];
                gt[g] = sum;
            }
            float ig = fast_sigmoid(gt[0]);
            float fg = fast_sigmoid(gt[1]);
            float gg = fast_tanh(gt[2]);
            float og = fast_sigmoid(gt[3]);
            cst = fg * cst + ig * gg;
            float h = og * fast_tanh(cst);
            // fire-and-forget write-through store to the coherence point
            __hip_atomic_store(&Yout[((long)(ub * Tt + tt)) * Hh + d * Ee + s * 12 + ur],
                               h, __ATOMIC_RELAXED, __HIP_MEMORY_SCOPE_AGENT);
            // prefetch next step's G (overlaps next staging)
            if (it != 127) {
                int ttn = d ? (tt - 1) : (tt + 1);
#pragma unroll
                for (int g = 0; g < 4; ++g) gpre[g] = gbase[(long)ttn * GATE + g * Ee];
            }
        }
    }
}

// ---------------------------------------------------------------------------
// Sentinel pre-fill (one launch for Y0+Y1 contiguous region and hs)
// ---------------------------------------------------------------------------
__global__ void k_fill_sent2(float* __restrict__ a, int na4,
                             float* __restrict__ b, int nb4)
{
    int i = blockIdx.x * 256 + threadIdx.x;
    unsigned u = 0xFFFFFFFFu;
    float f = __builtin_bit_cast(float, u);
    float4 f4 = make_float4(f, f, f, f);
    if (i < na4) ((float4*)a)[i] = f4;
    else {
        int j = i - na4;
        if (j < nb4) ((float4*)b)[j] = f4;
    }
}

// ---------------------------------------------------------------------------
// p_term (unchanged)
// ---------------------------------------------------------------------------
__global__ __launch_bounds__(256) void k_pterm(
    const float* __restrict__ hs, const int* __restrict__ qids,
    const float* __restrict__ Wp, float* __restrict__ pterm)
{
    int b = blockIdx.y;
    int chunk = blockIdx.x;
    int tid = threadIdx.x;
    int qid = qids[b];
    __shared__ float hp[Hh];
    for (int i = tid; i < Hh; i += 256) hp[i] = hs[((long)(b * Tt + qid)) * Hh + i];
    __syncthreads();
    int w = tid >> 6, lane = tid & 63;
#pragma unroll
    for (int r = 0; r < 8; ++r) {
        int n = chunk * 32 + w * 8 + r;
        const float* wrow = &Wp[(long)n * Hh];
        float p = 0.f;
#pragma unroll
        for (int k0 = 0; k0 < 3; ++k0) {
            int k = lane * 4 + k0 * 256;
            float4 wv = *(const float4*)&wrow[k];
            float4 hv = *(const float4*)&hp[k];
            p += wv.x * hv.x + wv.y * hv.y + wv.z * hv.z + wv.w * hv.w;
        }
#pragma unroll
        for (int o = 32; o; o >>= 1) p += __shfl_down(p, o);
        if (lane == 0) pterm[b * Hh + n] = p;
    }
}

// ---------------------------------------------------------------------------
// Fused attention (unchanged)
// ---------------------------------------------------------------------------
__global__ __launch_bounds__(256) void k_attn(
    const float* __restrict__ hs, const float* __restrict__ A1, const float* __restrict__ A2,
    const float* __restrict__ v, const float* __restrict__ Wclf,
    float* __restrict__ a_mat, float* __restrict__ logits)
{
    int b = blockIdx.x >> 7, t = blockIdx.x & 127;
    int tid = threadIdx.x;
    long bt = (long)(b * Tt + t);

    __shared__ float a2r[Hh], vr[Hh], hsr[Hh], crow[Hh];
    __shared__ float sc[128], tmp[256], red2[2];

    for (int i = tid; i < Hh; i += 256) {
        a2r[i] = A2[bt * Hh + i];
        vr[i] = v[i];
        hsr[i] = hs[bt * Hh + i];
    }
    __syncthreads();

    {
        int sid = tid >> 1, half = tid & 1;
        float p = 0.f;
        const float* A1r = &A1[((long)(b * Tt + sid)) * Hh + half * 384];
        const float* a2h = &a2r[half * 384];
        const float* vh = &vr[half * 384];
        for (int k = 0; k < 384; k += 4) {
            float4 z = *(const float4*)&A1r[k];
            p += vh[k + 0] * fast_tanh(z.x + a2h[k + 0]);
            p += vh[k + 1] * fast_tanh(z.y + a2h[k + 1]);
            p += vh[k + 2] * fast_tanh(z.z + a2h[k + 2]);
            p += vh[k + 3] * fast_tanh(z.w + a2h[k + 3]);
        }
        tmp[tid] = p;
    }
    __syncthreads();
    if (tid < 128) sc[tid] = tmp[2 * tid] + tmp[2 * tid + 1];
    __syncthreads();

    if (tid < 64) {
        float m = fmaxf(sc[tid], sc[tid + 64]);
#pragma unroll
        for (int o = 32; o; o >>= 1) m = fmaxf(m, __shfl_down(m, o));
        if (tid == 0) red2[0] = m;
    }
    __syncthreads();
    float mx = red2[0];
    if (tid < 128) sc[tid] = __expf(sc[tid] - mx);
    __syncthreads();
    if (tid < 64) {
        float sm = sc[tid] + sc[tid + 64];
#pragma unroll
        for (int o = 32; o; o >>= 1) sm += __shfl_down(sm, o);
        if (tid == 0) red2[1] = sm;
    }
    __syncthreads();
    float inv = 1.f / red2[1];
    if (tid < 128) {
        sc[tid] *= inv;
        a_mat[bt * 128 + tid] = sc[tid];
    }
    __syncthreads();

    float c0 = 0.f, c1 = 0.f, c2 = 0.f;
    for (int s2 = 0; s2 < 128; ++s2) {
        float as = sc[s2];
        const float* hrow = &hs[((long)(b * Tt + s2)) * Hh];
        c0 = fmaf(as, hrow[tid], c0);
        c1 = fmaf(as, hrow[tid + 256], c1);
        c2 = fmaf(as, hrow[tid + 512], c2);
    }
    crow[tid] = c0; crow[tid + 256] = c1; crow[tid + 512] = c2;
    __syncthreads();

    for (int l = 0; l < Ll; ++l) {
        float p = 0.f;
        for (int h = tid; h < 2 * Hh; h += 256) {
            float u = (h < Hh) ? hsr[h] : crow[h - Hh];
            p = fmaf(u, Wclf[l * 2 * Hh + h], p);
        }
#pragma unroll
        for (int o = 32; o; o >>= 1) p += __shfl_down(p, o);
        if ((tid & 63) == 0) tmp[tid >> 6] = p;
        __syncthreads();
        if (tid == 0) logits[bt * Ll + l] = tmp[0] + tmp[1] + tmp[2] + tmp[3];
        __syncthreads();
    }
}

// ---------------------------------------------------------------------------
// a_t normalization (unchanged)
// ---------------------------------------------------------------------------
__global__ void k_norm(const float* __restrict__ a_mat, float* __restrict__ a_t)
{
    int b = blockIdx.x;
    int s = threadIdx.x;
    float sum = 0.f;
    for (int t = 0; t < Tt; ++t) sum += a_mat[((long)(b * Tt + t)) * 128 + s];
    __shared__ float pool[128];
    __shared__ float tot;
    pool[s] = sum;
    __syncthreads();
    if (s < 64) {
        float v2 = pool[s] + pool[s + 64];
#pragma unroll
        for (int o = 32; o; o >>= 1) v2 += __shfl_down(v2, o);
        if (s == 0) tot = v2;
    }
    __syncthreads();
    float tv = tot;
    a_t[b * 128 + s] = (tv != 0.f) ? pool[s] / tv : 0.f;
}

// ---------------------------------------------------------------------------
// Viterbi (unchanged)
// ---------------------------------------------------------------------------
__global__ void k_viterbi(const float* __restrict__ logits, const float* __restrict__ trans,
                          const float* __restrict__ start, const float* __restrict__ endw,
                          float* __restrict__ out)
{
    __shared__ float sc[2][72];
    __shared__ unsigned char ptrs[127][72];
    __shared__ unsigned char tags[8][128];
    int tid = threadIdx.x;
    int b = tid / 9, j = tid % 9;
    bool act = tid < 72;
    if (act) sc[0][b * 9 + j] = start[j] + logits[(b * Tt + 0) * Ll + j];
    __syncthreads();
    for (int t = 1; t < Tt; ++t) {
        int cur = t & 1, prv = cur ^ 1;
        if (act) {
            float best = -1e30f; int bi = 0;
#pragma unroll
            for (int i = 0; i < 9; ++i) {
                float vv = sc[prv][b * 9 + i] + trans[i * 9 + j];
                if (vv > best) { best = vv; bi = i; }
            }
            sc[cur][b * 9 + j] = best + logits[(b * Tt + t) * Ll + j];
            ptrs[t - 1][b * 9 + j] = (unsigned char)bi;
        }
        __syncthreads();
    }
    if (act && j == 0) {
        float best = -1e30f; int bj = 0;
#pragma unroll
        for (int jj = 0; jj < 9; ++jj) {
            float vv = sc[1][b * 9 + jj] + endw[jj];
            if (vv > best) { best = vv; bj = jj; }
        }
        int tg = bj;
        tags[b][127] = (unsigned char)tg;
        for (int t = 127; t >= 1; --t) {
            tg = ptrs[t - 1][b * 9 + tg];
            tags[b][t - 1] = (unsigned char)tg;
        }
    }
    __syncthreads();
    for (int i = tid; i < Bq * Tt * Ll; i += blockDim.x) {
        int l = i % 9;
        int btx = i / 9;
        int tt2 = btx % Tt;
        int bb = btx / Tt;
        out[i] = (tags[bb][tt2] == l) ? 10.f : -1.f;
    }
}

// ---------------------------------------------------------------------------
extern "C" void kernel_launch(void* const* d_in, const int* in_sizes, int n_in,
                              void* d_out, int out_size, void* d_ws, size_t ws_size,
                              hipStream_t stream)
{
    const float* embeds   = (const float*)d_in[0];
    const int*   qids     = (const int*)d_in[1];
    const float* w_ih_l0  = (const float*)d_in[2];
    const float* w_ih_rest= (const float*)d_in[3];
    const float* w_hh     = (const float*)d_in[4];
    const float* b_ih     = (const float*)d_in[5];
    const float* b_hh     = (const float*)d_in[6];
    const float* W_H      = (const float*)d_in[7];
    const float* W_p      = (const float*)d_in[8];
    const float* W_h      = (const float*)d_in[9];
    const float* vvec     = (const float*)d_in[10];
    const float* W_clf    = (const float*)d_in[11];
    const float* trans    = (const float*)d_in[12];
    const float* cstart   = (const float*)d_in[13];
    const float* cend     = (const float*)d_in[14];

    float* out = (float*)d_out;
    float* vit_out = out;                          // 8*128*9   = 9216
    float* hs      = out + 9216;                   // 8*128*768 = 786432
    float* a_t     = out + 9216 + 786432;          // 8*128     = 1024

    float* ws = (float*)d_ws;
    float* G      = ws;                  // 3145728 floats
    float* Y0     = ws + 3145728;        // 786432
    float* Y1     = Y0 + 786432;         // 786432 (contiguous with Y0)
    float* A1     = ws;                  // reuses G (dead after last lstm)
    float* A2     = A1 + 786432;
    float* pterm  = A2 + 786432;
    float* a_mat  = pterm + 6144;
    float* logits = a_mat + 131072;

    dim3 blk(256);
    const int nY4 = 2 * 786432 / 4;      // Y0+Y1 float4 count
    const int nH4 = 786432 / 4;          // hs float4 count
    const int fillgrid = (nY4 + nH4 + 255) / 256;

    // Sentinel pre-fill of the three exchange buffers (one launch).
    k_fill_sent2<<<dim3(fillgrid), blk, 0, stream>>>(Y0, nY4, hs, nH4);

    // ---- Layer 0 ----
    k_gemm<<<dim3(GATE / BN, 1024 / BM, 2), blk, 0, stream>>>(
        embeds, w_ih_l0, G, 1024, GATE, Ee,
        0L, (long)GATE * Ee, (long)1024 * GATE,
        b_ih, b_hh, (long)GATE, nullptr);
    k_lstm<<<dim3(64), blk, 0, stream>>>(G, w_hh, Y0);

    // ---- Layer 1 ----
    k_gemm<<<dim3(GATE / BN, 1024 / BM, 2), blk, 0, stream>>>(
        Y0, w_ih_rest, G, 1024, GATE, Hh,
        0L, (long)GATE * Hh, (long)1024 * GATE,
        b_ih + 2 * GATE, b_hh + 2 * GATE, (long)GATE, nullptr);
    k_lstm<<<dim3(64), blk, 0, stream>>>(G, w_hh + (long)2 * GATE * Ee, Y1);

    // ---- Layer 2 ----
    k_gemm<<<dim3(GATE / BN, 1024 / BM, 2), blk, 0, stream>>>(
        Y1, w_ih_rest + (long)2 * GATE * Hh, G, 1024, GATE, Hh,
        0L, (long)GATE * Hh, (long)1024 * GATE,
        b_ih + 4 * GATE, b_hh + 4 * GATE, (long)GATE, nullptr);
    k_lstm<<<dim3(64), blk, 0, stream>>>(G, w_hh + (long)4 * GATE * Ee, hs);

    // ---- Attention precompute ----
    k_pterm<<<dim3(24, 8), blk, 0, stream>>>(hs, qids, W_p, pterm);
    k_gemm<<<dim3(Hh / BN, 1024 / BM, 1), blk, 0, stream>>>(
        hs, W_H, A1, 1024, Hh, Hh, 0L, 0L, 0L, nullptr, nullptr, 0L, nullptr);
    k_gemm<<<dim3(Hh / BN, 1024 / BM, 1), blk, 0, stream>>>(
        hs, W_h, A2, 1024, Hh, Hh, 0L, 0L, 0L, nullptr, nullptr, 0L, pterm);

    // ---- Fused attention + logits ----
    k_attn<<<dim3(1024), blk, 0, stream>>>(hs, A1, A2, vvec, W_clf, a_mat, logits);

    // ---- Pooled attention norm -> a_t ----
    k_norm<<<dim3(8), dim3(128), 0, stream>>>(a_mat, a_t);

    // ---- Viterbi -> vit_logits ----
    k_viterbi<<<dim3(1), dim3(128), 0, stream>>>(logits, trans, cstart, cend, vit_out);
}

// Round 11
// 2264.187 us; speedup vs baseline: 17.0850x; 1.0129x over previous
//
#include <hip/hip_runtime.h>
#include <math.h>

// Problem constants
#define Bq 8
#define Tt 128
#define Ee 384
#define Hh 768
#define Ll 9
#define GATE 1536   // 4*E

__device__ __forceinline__ float fast_sigmoid(float x) {
    return 1.f / (1.f + __expf(-x));
}
__device__ __forceinline__ float fast_tanh(float x) {
    return 1.f - 2.f / (__expf(2.f * x) + 1.f);
}

// ---------------------------------------------------------------------------
// Generic f32 GEMM, double-buffered LDS (1 sync/iter, global loads hidden
// under compute of the previous tile).
// C[m,n] = sum_k A[m,k]*Bw[n,k] + b1[n] + b2[n] + bbn[m>>7][n]
// ---------------------------------------------------------------------------
#define BM 128
#define BN 128
#define BKk 16

__global__ __launch_bounds__(256) void k_gemm(
    const float* __restrict__ A, const float* __restrict__ Bw, float* __restrict__ C,
    int M, int N, int K,
    long sAz, long sBz, long sCz,
    const float* __restrict__ b1, const float* __restrict__ b2, long sbz,
    const float* __restrict__ bbn)
{
    int z = blockIdx.z;
    A += (long)z * sAz;
    Bw += (long)z * sBz;
    C += (long)z * sCz;
    const float* bb1 = b1 ? b1 + (long)z * sbz : nullptr;
    const float* bb2 = b2 ? b2 + (long)z * sbz : nullptr;

    int n0 = blockIdx.x * BN;
    int m0 = blockIdx.y * BM;
    int tid = threadIdx.x;

    __shared__ float As[2][BKk][BM];
    __shared__ float Bs[2][BKk][BN];

    int lr = tid >> 2;          // 0..63
    int lc = (tid & 3) * 4;     // 0,4,8,12
    int tx = tid & 15;
    int ty = tid >> 4;

    float acc[8][8];
#pragma unroll
    for (int i = 0; i < 8; ++i)
#pragma unroll
        for (int j = 0; j < 8; ++j) acc[i][j] = 0.f;

    // preload tile 0 into LDS[0]
    {
        float4 a0 = *(const float4*)&A[(long)(m0 + lr) * K + lc];
        float4 a1 = *(const float4*)&A[(long)(m0 + lr + 64) * K + lc];
        float4 w0 = *(const float4*)&Bw[(long)(n0 + lr) * K + lc];
        float4 w1 = *(const float4*)&Bw[(long)(n0 + lr + 64) * K + lc];
        As[0][lc + 0][lr] = a0.x; As[0][lc + 1][lr] = a0.y; As[0][lc + 2][lr] = a0.z; As[0][lc + 3][lr] = a0.w;
        As[0][lc + 0][lr + 64] = a1.x; As[0][lc + 1][lr + 64] = a1.y; As[0][lc + 2][lr + 64] = a1.z; As[0][lc + 3][lr + 64] = a1.w;
        Bs[0][lc + 0][lr] = w0.x; Bs[0][lc + 1][lr] = w0.y; Bs[0][lc + 2][lr] = w0.z; Bs[0][lc + 3][lr] = w0.w;
        Bs[0][lc + 0][lr + 64] = w1.x; Bs[0][lc + 1][lr + 64] = w1.y; Bs[0][lc + 2][lr + 64] = w1.z; Bs[0][lc + 3][lr + 64] = w1.w;
    }
    __syncthreads();

    int steps = K / BKk;
    for (int k0 = 0; k0 < steps; ++k0) {
        int cur = k0 & 1, nxt = cur ^ 1;
        float4 na0, na1, nw0, nw1;
        bool havenext = (k0 + 1 < steps);
        if (havenext) {
            int kb = (k0 + 1) * BKk;
            na0 = *(const float4*)&A[(long)(m0 + lr) * K + kb + lc];
            na1 = *(const float4*)&A[(long)(m0 + lr + 64) * K + kb + lc];
            nw0 = *(const float4*)&Bw[(long)(n0 + lr) * K + kb + lc];
            nw1 = *(const float4*)&Bw[(long)(n0 + lr + 64) * K + kb + lc];
        }
#pragma unroll
        for (int kk = 0; kk < BKk; ++kk) {
            float av[8], bv[8];
            *(float4*)&av[0] = *(float4*)&As[cur][kk][ty * 8];
            *(float4*)&av[4] = *(float4*)&As[cur][kk][ty * 8 + 4];
            *(float4*)&bv[0] = *(float4*)&Bs[cur][kk][tx * 8];
            *(float4*)&bv[4] = *(float4*)&Bs[cur][kk][tx * 8 + 4];
#pragma unroll
            for (int i = 0; i < 8; ++i)
#pragma unroll
                for (int j = 0; j < 8; ++j)
                    acc[i][j] = fmaf(av[i], bv[j], acc[i][j]);
        }
        if (havenext) {
            As[nxt][lc + 0][lr] = na0.x; As[nxt][lc + 1][lr] = na0.y; As[nxt][lc + 2][lr] = na0.z; As[nxt][lc + 3][lr] = na0.w;
            As[nxt][lc + 0][lr + 64] = na1.x; As[nxt][lc + 1][lr + 64] = na1.y; As[nxt][lc + 2][lr + 64] = na1.z; As[nxt][lc + 3][lr + 64] = na1.w;
            Bs[nxt][lc + 0][lr] = nw0.x; Bs[nxt][lc + 1][lr] = nw0.y; Bs[nxt][lc + 2][lr] = nw0.z; Bs[nxt][lc + 3][lr] = nw0.w;
            Bs[nxt][lc + 0][lr + 64] = nw1.x; Bs[nxt][lc + 1][lr + 64] = nw1.y; Bs[nxt][lc + 2][lr + 64] = nw1.z; Bs[nxt][lc + 3][lr + 64] = nw1.w;
        }
        __syncthreads();
    }

#pragma unroll
    for (int i = 0; i < 8; ++i) {
        long m = m0 + ty * 8 + i;
#pragma unroll
        for (int j = 0; j < 8; ++j) {
            int n = n0 + tx * 8 + j;
            float val = acc[i][j];
            if (bb1) val += bb1[n];
            if (bb2) val += bb2[n];
            if (bbn) val += bbn[(m >> 7) * (long)N + n];
            C[m * N + n] = val;
        }
    }
}

// ---------------------------------------------------------------------------
// LSTM recurrence, sentinel-dataflow with SWEEP polling: each sweep re-issues
// loads for ALL missing words back-to-back (independent, overlapped) so k
// misses cost ~1 RTT/sweep instead of k serialized RTTs.
// 64 blocks: d = bid>>5, slice s = bid&31 owns h-rows s*12..s*12+11.
// Thread (kq=tid>>4: 24-k range, rg=tid&15: 3 gate rows); W 72 floats/thread
// register-resident. Yout pre-filled with 0xFFFFFFFF (NaN); h always finite.
// ---------------------------------------------------------------------------
__device__ __forceinline__ bool has_sent(unsigned long long v) {
    return ((unsigned)v == 0xFFFFFFFFu) || ((unsigned)(v >> 32) == 0xFFFFFFFFu);
}

__global__ __launch_bounds__(256, 1) void k_lstm(
    const float* __restrict__ G, const float* __restrict__ Whh, float* Yout)
{
    int bid = blockIdx.x;
    int d = bid >> 5;           // direction
    int s = bid & 31;           // slice: h-rows s*12..s*12+11
    int tid = threadIdx.x;
    int kq = tid >> 4;          // 0..15 (k-range of 24)
    int rg = tid & 15;          // 0..15 (3 gate-rows each)
    int kq24 = kq * 24;

    __shared__ float hl[8 * 384];       // h_prev for all batches of this dir
    __shared__ float part[16 * 392];    // [kq][b(stride 49)][rl 0..47]

    // W slice: 3 gate rows x 24 k = 72 floats (register-resident)
    float W_[3][24];
    const float* Wd = Whh + (long)d * GATE * Ee;
#pragma unroll
    for (int r = 0; r < 3; ++r) {
        int rl = rg * 3 + r;            // 0..47
        int g = rl / 12, rr = rl % 12;
        const float* src = Wd + (long)(g * Ee + s * 12 + rr) * Ee + kq24;
#pragma unroll
        for (int k4 = 0; k4 < 6; ++k4) {
            float4 w = *(const float4*)&src[k4 * 4];
            W_[r][k4 * 4 + 0] = w.x;
            W_[r][k4 * 4 + 1] = w.y;
            W_[r][k4 * 4 + 2] = w.z;
            W_[r][k4 * 4 + 3] = w.w;
        }
    }

    float cst = 0.f;                    // cell state for update thread
    bool upd = tid < 96;
    int ub = upd ? (tid / 12) : 0;      // batch
    int ur = upd ? (tid - ub * 12) : 0; // h-row within slice

    // G prefetch (one timestep ahead)
    float gpre[4];
    const float* gbase = G + ((long)d * 1024 + ub * Tt) * GATE + s * 12 + ur;
    {
        int tt0 = d ? 127 : 0;
        if (upd) {
#pragma unroll
            for (int g = 0; g < 4; ++g) gpre[g] = gbase[(long)tt0 * GATE + g * Ee];
        }
    }

    float4* hl4 = (float4*)hl;

    for (int it = 0; it < 128; ++it) {
        int tt = d ? (127 - it) : it;
        int tp = d ? (tt + 1) : (tt - 1);

        // stage h_{prev}: parallel-issue all 6 words, sweep-verify
        if (it == 0) {
            float4 z4 = make_float4(0.f, 0.f, 0.f, 0.f);
#pragma unroll
            for (int ii = 0; ii < 3; ++ii) hl4[tid + 256 * ii] = z4;
        } else {
            const unsigned long long* sp[6];
            unsigned long long v[6];
#pragma unroll
            for (int ii = 0; ii < 3; ++ii) {
                int i4 = tid + 256 * ii;       // 0..767
                int b = i4 / 96, k4 = i4 - b * 96;
                const unsigned long long* base = (const unsigned long long*)
                    &Yout[((long)(b * Tt + tp)) * Hh + d * Ee + k4 * 4];
                sp[2 * ii] = base;
                sp[2 * ii + 1] = base + 1;
            }
#pragma unroll
            for (int j = 0; j < 6; ++j)
                v[j] = __hip_atomic_load(sp[j], __ATOMIC_RELAXED, __HIP_MEMORY_SCOPE_AGENT);
            for (;;) {
                bool any = false;
#pragma unroll
                for (int j = 0; j < 6; ++j) {
                    if (has_sent(v[j])) {
                        v[j] = __hip_atomic_load(sp[j], __ATOMIC_RELAXED, __HIP_MEMORY_SCOPE_AGENT);
                        any = true;
                    }
                }
                if (!any) break;
            }
#pragma unroll
            for (int ii = 0; ii < 3; ++ii) {
                int i4 = tid + 256 * ii;
                float2 flo = __builtin_bit_cast(float2, v[2 * ii]);
                float2 fhi = __builtin_bit_cast(float2, v[2 * ii + 1]);
                hl4[i4] = make_float4(flo.x, flo.y, fhi.x, fhi.y);
            }
        }
        __syncthreads();

        float acc[8][3];
#pragma unroll
        for (int b = 0; b < 8; ++b)
#pragma unroll
            for (int r = 0; r < 3; ++r) acc[b][r] = 0.f;

#pragma unroll
        for (int k4 = 0; k4 < 6; ++k4) {
#pragma unroll
            for (int b = 0; b < 8; ++b) {
                float4 hv = *(const float4*)&hl[b * 384 + kq24 + k4 * 4];
#pragma unroll
                for (int r = 0; r < 3; ++r) {
                    acc[b][r] = fmaf(W_[r][k4 * 4 + 0], hv.x, acc[b][r]);
                    acc[b][r] = fmaf(W_[r][k4 * 4 + 1], hv.y, acc[b][r]);
                    acc[b][r] = fmaf(W_[r][k4 * 4 + 2], hv.z, acc[b][r]);
                    acc[b][r] = fmaf(W_[r][k4 * 4 + 3], hv.w, acc[b][r]);
                }
            }
        }

        // write partials
#pragma unroll
        for (int b = 0; b < 8; ++b)
#pragma unroll
            for (int r = 0; r < 3; ++r)
                part[kq * 392 + b * 49 + rg * 3 + r] = acc[b][r];
        __syncthreads();

        if (upd) {
            float gt[4];
#pragma unroll
            for (int g = 0; g < 4; ++g) {
                int rl = g * 12 + ur;
                float sum = gpre[g];
#pragma unroll
                for (int q = 0; q < 16; ++q) sum += part[q * 392 + ub * 49 + rl];
                gt[g] = sum;
            }
            float ig = fast_sigmoid(gt[0]);
            float fg = fast_sigmoid(gt[1]);
            float gg = fast_tanh(gt[2]);
            float og = fast_sigmoid(gt[3]);
            cst = fg * cst + ig * gg;
            float h = og * fast_tanh(cst);
            // fire-and-forget write-through store to the coherence point
            __hip_atomic_store(&Yout[((long)(ub * Tt + tt)) * Hh + d * Ee + s * 12 + ur],
                               h, __ATOMIC_RELAXED, __HIP_MEMORY_SCOPE_AGENT);
            // prefetch next step's G (overlaps next staging)
            if (it != 127) {
                int ttn = d ? (tt - 1) : (tt + 1);
#pragma unroll
                for (int g = 0; g < 4; ++g) gpre[g] = gbase[(long)ttn * GATE + g * Ee];
            }
        }
    }
}

// ---------------------------------------------------------------------------
// Sentinel pre-fill (one launch for Y0+Y1 contiguous region and hs)
// ---------------------------------------------------------------------------
__global__ void k_fill_sent2(float* __restrict__ a, int na4,
                             float* __restrict__ b, int nb4)
{
    int i = blockIdx.x * 256 + threadIdx.x;
    unsigned u = 0xFFFFFFFFu;
    float f = __builtin_bit_cast(float, u);
    float4 f4 = make_float4(f, f, f, f);
    if (i < na4) ((float4*)a)[i] = f4;
    else {
        int j = i - na4;
        if (j < nb4) ((float4*)b)[j] = f4;
    }
}

// ---------------------------------------------------------------------------
// p_term (unchanged)
// ---------------------------------------------------------------------------
__global__ __launch_bounds__(256) void k_pterm(
    const float* __restrict__ hs, const int* __restrict__ qids,
    const float* __restrict__ Wp, float* __restrict__ pterm)
{
    int b = blockIdx.y;
    int chunk = blockIdx.x;
    int tid = threadIdx.x;
    int qid = qids[b];
    __shared__ float hp[Hh];
    for (int i = tid; i < Hh; i += 256) hp[i] = hs[((long)(b * Tt + qid)) * Hh + i];
    __syncthreads();
    int w = tid >> 6, lane = tid & 63;
#pragma unroll
    for (int r = 0; r < 8; ++r) {
        int n = chunk * 32 + w * 8 + r;
        const float* wrow = &Wp[(long)n * Hh];
        float p = 0.f;
#pragma unroll
        for (int k0 = 0; k0 < 3; ++k0) {
            int k = lane * 4 + k0 * 256;
            float4 wv = *(const float4*)&wrow[k];
            float4 hv = *(const float4*)&hp[k];
            p += wv.x * hv.x + wv.y * hv.y + wv.z * hv.z + wv.w * hv.w;
        }
#pragma unroll
        for (int o = 32; o; o >>= 1) p += __shfl_down(p, o);
        if (lane == 0) pterm[b * Hh + n] = p;
    }
}

// ---------------------------------------------------------------------------
// Fused attention (unchanged)
// ---------------------------------------------------------------------------
__global__ __launch_bounds__(256) void k_attn(
    const float* __restrict__ hs, const float* __restrict__ A1, const float* __restrict__ A2,
    const float* __restrict__ v, const float* __restrict__ Wclf,
    float* __restrict__ a_mat, float* __restrict__ logits)
{
    int b = blockIdx.x >> 7, t = blockIdx.x & 127;
    int tid = threadIdx.x;
    long bt = (long)(b * Tt + t);

    __shared__ float a2r[Hh], vr[Hh], hsr[Hh], crow[Hh];
    __shared__ float sc[128], tmp[256], red2[2];

    for (int i = tid; i < Hh; i += 256) {
        a2r[i] = A2[bt * Hh + i];
        vr[i] = v[i];
        hsr[i] = hs[bt * Hh + i];
    }
    __syncthreads();

    {
        int sid = tid >> 1, half = tid & 1;
        float p = 0.f;
        const float* A1r = &A1[((long)(b * Tt + sid)) * Hh + half * 384];
        const float* a2h = &a2r[half * 384];
        const float* vh = &vr[half * 384];
        for (int k = 0; k < 384; k += 4) {
            float4 z = *(const float4*)&A1r[k];
            p += vh[k + 0] * fast_tanh(z.x + a2h[k + 0]);
            p += vh[k + 1] * fast_tanh(z.y + a2h[k + 1]);
            p += vh[k + 2] * fast_tanh(z.z + a2h[k + 2]);
            p += vh[k + 3] * fast_tanh(z.w + a2h[k + 3]);
        }
        tmp[tid] = p;
    }
    __syncthreads();
    if (tid < 128) sc[tid] = tmp[2 * tid] + tmp[2 * tid + 1];
    __syncthreads();

    if (tid < 64) {
        float m = fmaxf(sc[tid], sc[tid + 64]);
#pragma unroll
        for (int o = 32; o; o >>= 1) m = fmaxf(m, __shfl_down(m, o));
        if (tid == 0) red2[0] = m;
    }
    __syncthreads();
    float mx = red2[0];
    if (tid < 128) sc[tid] = __expf(sc[tid] - mx);
    __syncthreads();
    if (tid < 64) {
        float sm = sc[tid] + sc[tid + 64];
#pragma unroll
        for (int o = 32; o; o >>= 1) sm += __shfl_down(sm, o);
        if (tid == 0) red2[1] = sm;
    }
    __syncthreads();
    float inv = 1.f / red2[1];
    if (tid < 128) {
        sc[tid] *= inv;
        a_mat[bt * 128 + tid] = sc[tid];
    }
    __syncthreads();

    float c0 = 0.f, c1 = 0.f, c2 = 0.f;
    for (int s2 = 0; s2 < 128; ++s2) {
        float as = sc[s2];
        const float* hrow = &hs[((long)(b * Tt + s2)) * Hh];
        c0 = fmaf(as, hrow[tid], c0);
        c1 = fmaf(as, hrow[tid + 256], c1);
        c2 = fmaf(as, hrow[tid + 512], c2);
    }
    crow[tid] = c0; crow[tid + 256] = c1; crow[tid + 512] = c2;
    __syncthreads();

    for (int l = 0; l < Ll; ++l) {
        float p = 0.f;
        for (int h = tid; h < 2 * Hh; h += 256) {
            float u = (h < Hh) ? hsr[h] : crow[h - Hh];
            p = fmaf(u, Wclf[l * 2 * Hh + h], p);
        }
#pragma unroll
        for (int o = 32; o; o >>= 1) p += __shfl_down(p, o);
        if ((tid & 63) == 0) tmp[tid >> 6] = p;
        __syncthreads();
        if (tid == 0) logits[bt * Ll + l] = tmp[0] + tmp[1] + tmp[2] + tmp[3];
        __syncthreads();
    }
}

// ---------------------------------------------------------------------------
// a_t normalization (unchanged)
// ---------------------------------------------------------------------------
__global__ void k_norm(const float* __restrict__ a_mat, float* __restrict__ a_t)
{
    int b = blockIdx.x;
    int s = threadIdx.x;
    float sum = 0.f;
    for (int t = 0; t < Tt; ++t) sum += a_mat[((long)(b * Tt + t)) * 128 + s];
    __shared__ float pool[128];
    __shared__ float tot;
    pool[s] = sum;
    __syncthreads();
    if (s < 64) {
        float v2 = pool[s] + pool[s + 64];
#pragma unroll
        for (int o = 32; o; o >>= 1) v2 += __shfl_down(v2, o);
        if (s == 0) tot = v2;
    }
    __syncthreads();
    float tv = tot;
    a_t[b * 128 + s] = (tv != 0.f) ? pool[s] / tv : 0.f;
}

// ---------------------------------------------------------------------------
// Viterbi (unchanged)
// ---------------------------------------------------------------------------
__global__ void k_viterbi(const float* __restrict__ logits, const float* __restrict__ trans,
                          const float* __restrict__ start, const float* __restrict__ endw,
                          float* __restrict__ out)
{
    __shared__ float sc[2][72];
    __shared__ unsigned char ptrs[127][72];
    __shared__ unsigned char tags[8][128];
    int tid = threadIdx.x;
    int b = tid / 9, j = tid % 9;
    bool act = tid < 72;
    if (act) sc[0][b * 9 + j] = start[j] + logits[(b * Tt + 0) * Ll + j];
    __syncthreads();
    for (int t = 1; t < Tt; ++t) {
        int cur = t & 1, prv = cur ^ 1;
        if (act) {
            float best = -1e30f; int bi = 0;
#pragma unroll
            for (int i = 0; i < 9; ++i) {
                float vv = sc[prv][b * 9 + i] + trans[i * 9 + j];
                if (vv > best) { best = vv; bi = i; }
            }
            sc[cur][b * 9 + j] = best + logits[(b * Tt + t) * Ll + j];
            ptrs[t - 1][b * 9 + j] = (unsigned char)bi;
        }
        __syncthreads();
    }
    if (act && j == 0) {
        float best = -1e30f; int bj = 0;
#pragma unroll
        for (int jj = 0; jj < 9; ++jj) {
            float vv = sc[1][b * 9 + jj] + endw[jj];
            if (vv > best) { best = vv; bj = jj; }
        }
        int tg = bj;
        tags[b][127] = (unsigned char)tg;
        for (int t = 127; t >= 1; --t) {
            tg = ptrs[t - 1][b * 9 + tg];
            tags[b][t - 1] = (unsigned char)tg;
        }
    }
    __syncthreads();
    for (int i = tid; i < Bq * Tt * Ll; i += blockDim.x) {
        int l = i % 9;
        int btx = i / 9;
        int tt2 = btx % Tt;
        int bb = btx / Tt;
        out[i] = (tags[bb][tt2] == l) ? 10.f : -1.f;
    }
}

// ---------------------------------------------------------------------------
extern "C" void kernel_launch(void* const* d_in, const int* in_sizes, int n_in,
                              void* d_out, int out_size, void* d_ws, size_t ws_size,
                              hipStream_t stream)
{
    const float* embeds   = (const float*)d_in[0];
    const int*   qids     = (const int*)d_in[1];
    const float* w_ih_l0  = (const float*)d_in[2];
    const float* w_ih_rest= (const float*)d_in[3];
    const float* w_hh     = (const float*)d_in[4];
    const float* b_ih     = (const float*)d_in[5];
    const float* b_hh     = (const float*)d_in[6];
    const float* W_H      = (const float*)d_in[7];
    const float* W_p      = (const float*)d_in[8];
    const float* W_h      = (const float*)d_in[9];
    const float* vvec     = (const float*)d_in[10];
    const float* W_clf    = (const float*)d_in[11];
    const float* trans    = (const float*)d_in[12];
    const float* cstart   = (const float*)d_in[13];
    const float* cend     = (const float*)d_in[14];

    float* out = (float*)d_out;
    float* vit_out = out;                          // 8*128*9   = 9216
    float* hs      = out + 9216;                   // 8*128*768 = 786432
    float* a_t     = out + 9216 + 786432;          // 8*128     = 1024

    float* ws = (float*)d_ws;
    float* G      = ws;                  // 3145728 floats
    float* Y0     = ws + 3145728;        // 786432
    float* Y1     = Y0 + 786432;         // 786432 (contiguous with Y0)
    float* A1     = ws;                  // reuses G (dead after last lstm)
    float* A2     = A1 + 786432;
    float* pterm  = A2 + 786432;
    float* a_mat  = pterm + 6144;
    float* logits = a_mat + 131072;

    dim3 blk(256);
    const int nY4 = 2 * 786432 / 4;      // Y0+Y1 float4 count
    const int nH4 = 786432 / 4;          // hs float4 count
    const int fillgrid = (nY4 + nH4 + 255) / 256;

    // Sentinel pre-fill of the three exchange buffers (one launch).
    k_fill_sent2<<<dim3(fillgrid), blk, 0, stream>>>(Y0, nY4, hs, nH4);

    // ---- Layer 0 ----
    k_gemm<<<dim3(GATE / BN, 1024 / BM, 2), blk, 0, stream>>>(
        embeds, w_ih_l0, G, 1024, GATE, Ee,
        0L, (long)GATE * Ee, (long)1024 * GATE,
        b_ih, b_hh, (long)GATE, nullptr);
    k_lstm<<<dim3(64), blk, 0, stream>>>(G, w_hh, Y0);

    // ---- Layer 1 ----
    k_gemm<<<dim3(GATE / BN, 1024 / BM, 2), blk, 0, stream>>>(
        Y0, w_ih_rest, G, 1024, GATE, Hh,
        0L, (long)GATE * Hh, (long)1024 * GATE,
        b_ih + 2 * GATE, b_hh + 2 * GATE, (long)GATE, nullptr);
    k_lstm<<<dim3(64), blk, 0, stream>>>(G, w_hh + (long)2 * GATE * Ee, Y1);

    // ---- Layer 2 ----
    k_gemm<<<dim3(GATE / BN, 1024 / BM, 2), blk, 0, stream>>>(
        Y1, w_ih_rest + (long)2 * GATE * Hh, G, 1024, GATE, Hh,
        0L, (long)GATE * Hh, (long)1024 * GATE,
        b_ih + 4 * GATE, b_hh + 4 * GATE, (long)GATE, nullptr);
    k_lstm<<<dim3(64), blk, 0, stream>>>(G, w_hh + (long)4 * GATE * Ee, hs);

    // ---- Attention precompute ----
    k_pterm<<<dim3(24, 8), blk, 0, stream>>>(hs, qids, W_p, pterm);
    k_gemm<<<dim3(Hh / BN, 1024 / BM, 1), blk, 0, stream>>>(
        hs, W_H, A1, 1024, Hh, Hh, 0L, 0L, 0L, nullptr, nullptr, 0L, nullptr);
    k_gemm<<<dim3(Hh / BN, 1024 / BM, 1), blk, 0, stream>>>(
        hs, W_h, A2, 1024, Hh, Hh, 0L, 0L, 0L, nullptr, nullptr, 0L, pterm);

    // ---- Fused attention + logits ----
    k_attn<<<dim3(1024), blk, 0, stream>>>(hs, A1, A2, vvec, W_clf, a_mat, logits);

    // ---- Pooled attention norm -> a_t ----
    k_norm<<<dim3(8), dim3(128), 0, stream>>>(a_mat, a_t);

    // ---- Viterbi -> vit_logits ----
    k_viterbi<<<dim3(1), dim3(128), 0, stream>>>(logits, trans, cstart, cend, vit_out);
}

// Round 12
// 1952.574 us; speedup vs baseline: 19.8116x; 1.1596x over previous
//
#include <hip/hip_runtime.h>
#include <math.h>

// Problem constants
#define Bq 8
#define Tt 128
#define Ee 384
#define Hh 768
#define Ll 9
#define GATE 1536   // 4*E

__device__ __forceinline__ float fast_sigmoid(float x) {
    return 1.f / (1.f + __expf(-x));
}
__device__ __forceinline__ float fast_tanh(float x) {
    return 1.f - 2.f / (__expf(2.f * x) + 1.f);
}

// ---------------------------------------------------------------------------
// Generic f32 GEMM, 64x64 tiles for occupancy (768-block grids -> 3 blocks/CU
// = 12 waves/CU; inter-wave overlap hides global latency, m114).
// C[m,n] = sum_k A[m,k]*Bw[n,k] + b1[n] + b2[n] + bbn[m>>7][n]
// A row-major (M,K), Bw row-major (N,K), C row-major (M,N).
// ---------------------------------------------------------------------------
#define BM 64
#define BN 64
#define BKk 16

__global__ __launch_bounds__(256) void k_gemm(
    const float* __restrict__ A, const float* __restrict__ Bw, float* __restrict__ C,
    int M, int N, int K,
    long sAz, long sBz, long sCz,
    const float* __restrict__ b1, const float* __restrict__ b2, long sbz,
    const float* __restrict__ bbn)
{
    int z = blockIdx.z;
    A += (long)z * sAz;
    Bw += (long)z * sBz;
    C += (long)z * sCz;
    const float* bb1 = b1 ? b1 + (long)z * sbz : nullptr;
    const float* bb2 = b2 ? b2 + (long)z * sbz : nullptr;

    int n0 = blockIdx.x * BN;
    int m0 = blockIdx.y * BM;
    int tid = threadIdx.x;

    __shared__ float As[BKk][BM];
    __shared__ float Bs[BKk][BN];

    int lr = tid & 63;          // row within tile
    int lc = (tid >> 6) * 4;    // col group 0,4,8,12
    int tx = tid & 15;          // microtile col
    int ty = tid >> 4;          // microtile row

    float acc[4][4];
#pragma unroll
    for (int i = 0; i < 4; ++i)
#pragma unroll
        for (int j = 0; j < 4; ++j) acc[i][j] = 0.f;

    for (int k0 = 0; k0 < K; k0 += BKk) {
        float4 a0 = *(const float4*)&A[(long)(m0 + lr) * K + k0 + lc];
        float4 w0 = *(const float4*)&Bw[(long)(n0 + lr) * K + k0 + lc];
        __syncthreads();
        As[lc + 0][lr] = a0.x; As[lc + 1][lr] = a0.y; As[lc + 2][lr] = a0.z; As[lc + 3][lr] = a0.w;
        Bs[lc + 0][lr] = w0.x; Bs[lc + 1][lr] = w0.y; Bs[lc + 2][lr] = w0.z; Bs[lc + 3][lr] = w0.w;
        __syncthreads();
#pragma unroll
        for (int kk = 0; kk < BKk; ++kk) {
            float av[4], bv[4];
            *(float4*)&av[0] = *(float4*)&As[kk][ty * 4];
            *(float4*)&bv[0] = *(float4*)&Bs[kk][tx * 4];
#pragma unroll
            for (int i = 0; i < 4; ++i)
#pragma unroll
                for (int j = 0; j < 4; ++j)
                    acc[i][j] = fmaf(av[i], bv[j], acc[i][j]);
        }
    }

#pragma unroll
    for (int i = 0; i < 4; ++i) {
        long m = m0 + ty * 4 + i;
#pragma unroll
        for (int j = 0; j < 4; ++j) {
            int n = n0 + tx * 4 + j;
            float val = acc[i][j];
            if (bb1) val += bb1[n];
            if (bb2) val += bb2[n];
            if (bbn) val += bbn[(m >> 7) * (long)N + n];
            C[m * N + n] = val;
        }
    }
}

// ---------------------------------------------------------------------------
// LSTM recurrence, sentinel-dataflow with SWEEP polling (unchanged from R11,
// 497 us/layer). 64 blocks: d = bid>>5, slice s = bid&31 owns h-rows
// s*12..s*12+11. W 72 floats/thread register-resident (VGPR=104, no spill).
// Yout pre-filled with 0xFFFFFFFF (NaN); h always finite.
// ---------------------------------------------------------------------------
__device__ __forceinline__ bool has_sent(unsigned long long v) {
    return ((unsigned)v == 0xFFFFFFFFu) || ((unsigned)(v >> 32) == 0xFFFFFFFFu);
}

__global__ __launch_bounds__(256, 1) void k_lstm(
    const float* __restrict__ G, const float* __restrict__ Whh, float* Yout)
{
    int bid = blockIdx.x;
    int d = bid >> 5;           // direction
    int s = bid & 31;           // slice: h-rows s*12..s*12+11
    int tid = threadIdx.x;
    int kq = tid >> 4;          // 0..15 (k-range of 24)
    int rg = tid & 15;          // 0..15 (3 gate-rows each)
    int kq24 = kq * 24;

    __shared__ float hl[8 * 384];       // h_prev for all batches of this dir
    __shared__ float part[16 * 392];    // [kq][b(stride 49)][rl 0..47]

    // W slice: 3 gate rows x 24 k = 72 floats (register-resident)
    float W_[3][24];
    const float* Wd = Whh + (long)d * GATE * Ee;
#pragma unroll
    for (int r = 0; r < 3; ++r) {
        int rl = rg * 3 + r;            // 0..47
        int g = rl / 12, rr = rl % 12;
        const float* src = Wd + (long)(g * Ee + s * 12 + rr) * Ee + kq24;
#pragma unroll
        for (int k4 = 0; k4 < 6; ++k4) {
            float4 w = *(const float4*)&src[k4 * 4];
            W_[r][k4 * 4 + 0] = w.x;
            W_[r][k4 * 4 + 1] = w.y;
            W_[r][k4 * 4 + 2] = w.z;
            W_[r][k4 * 4 + 3] = w.w;
        }
    }

    float cst = 0.f;                    // cell state for update thread
    bool upd = tid < 96;
    int ub = upd ? (tid / 12) : 0;      // batch
    int ur = upd ? (tid - ub * 12) : 0; // h-row within slice

    // G prefetch (one timestep ahead)
    float gpre[4];
    const float* gbase = G + ((long)d * 1024 + ub * Tt) * GATE + s * 12 + ur;
    {
        int tt0 = d ? 127 : 0;
        if (upd) {
#pragma unroll
            for (int g = 0; g < 4; ++g) gpre[g] = gbase[(long)tt0 * GATE + g * Ee];
        }
    }

    float4* hl4 = (float4*)hl;

    for (int it = 0; it < 128; ++it) {
        int tt = d ? (127 - it) : it;
        int tp = d ? (tt + 1) : (tt - 1);

        // stage h_{prev}: parallel-issue all 6 words, sweep-verify
        if (it == 0) {
            float4 z4 = make_float4(0.f, 0.f, 0.f, 0.f);
#pragma unroll
            for (int ii = 0; ii < 3; ++ii) hl4[tid + 256 * ii] = z4;
        } else {
            const unsigned long long* sp[6];
            unsigned long long v[6];
#pragma unroll
            for (int ii = 0; ii < 3; ++ii) {
                int i4 = tid + 256 * ii;       // 0..767
                int b = i4 / 96, k4 = i4 - b * 96;
                const unsigned long long* base = (const unsigned long long*)
                    &Yout[((long)(b * Tt + tp)) * Hh + d * Ee + k4 * 4];
                sp[2 * ii] = base;
                sp[2 * ii + 1] = base + 1;
            }
#pragma unroll
            for (int j = 0; j < 6; ++j)
                v[j] = __hip_atomic_load(sp[j], __ATOMIC_RELAXED, __HIP_MEMORY_SCOPE_AGENT);
            for (;;) {
                bool any = false;
#pragma unroll
                for (int j = 0; j < 6; ++j) {
                    if (has_sent(v[j])) {
                        v[j] = __hip_atomic_load(sp[j], __ATOMIC_RELAXED, __HIP_MEMORY_SCOPE_AGENT);
                        any = true;
                    }
                }
                if (!any) break;
            }
#pragma unroll
            for (int ii = 0; ii < 3; ++ii) {
                int i4 = tid + 256 * ii;
                float2 flo = __builtin_bit_cast(float2, v[2 * ii]);
                float2 fhi = __builtin_bit_cast(float2, v[2 * ii + 1]);
                hl4[i4] = make_float4(flo.x, flo.y, fhi.x, fhi.y);
            }
        }
        __syncthreads();

        float acc[8][3];
#pragma unroll
        for (int b = 0; b < 8; ++b)
#pragma unroll
            for (int r = 0; r < 3; ++r) acc[b][r] = 0.f;

#pragma unroll
        for (int k4 = 0; k4 < 6; ++k4) {
#pragma unroll
            for (int b = 0; b < 8; ++b) {
                float4 hv = *(const float4*)&hl[b * 384 + kq24 + k4 * 4];
#pragma unroll
                for (int r = 0; r < 3; ++r) {
                    acc[b][r] = fmaf(W_[r][k4 * 4 + 0], hv.x, acc[b][r]);
                    acc[b][r] = fmaf(W_[r][k4 * 4 + 1], hv.y, acc[b][r]);
                    acc[b][r] = fmaf(W_[r][k4 * 4 + 2], hv.z, acc[b][r]);
                    acc[b][r] = fmaf(W_[r][k4 * 4 + 3], hv.w, acc[b][r]);
                }
            }
        }

        // write partials
#pragma unroll
        for (int b = 0; b < 8; ++b)
#pragma unroll
            for (int r = 0; r < 3; ++r)
                part[kq * 392 + b * 49 + rg * 3 + r] = acc[b][r];
        __syncthreads();

        if (upd) {
            float gt[4];
#pragma unroll
            for (int g = 0; g < 4; ++g) {
                int rl = g * 12 + ur;
                float sum = gpre[g];
#pragma unroll
                for (int q = 0; q < 16; ++q) sum += part[q * 392 + ub * 49 + rl];
                gt[g] = sum;
            }
            float ig = fast_sigmoid(gt[0]);
            float fg = fast_sigmoid(gt[1]);
            float gg = fast_tanh(gt[2]);
            float og = fast_sigmoid(gt[3]);
            cst = fg * cst + ig * gg;
            float h = og * fast_tanh(cst);
            // fire-and-forget write-through store to the coherence point
            __hip_atomic_store(&Yout[((long)(ub * Tt + tt)) * Hh + d * Ee + s * 12 + ur],
                               h, __ATOMIC_RELAXED, __HIP_MEMORY_SCOPE_AGENT);
            // prefetch next step's G (overlaps next staging)
            if (it != 127) {
                int ttn = d ? (tt - 1) : (tt + 1);
#pragma unroll
                for (int g = 0; g < 4; ++g) gpre[g] = gbase[(long)ttn * GATE + g * Ee];
            }
        }
    }
}

// ---------------------------------------------------------------------------
// Sentinel pre-fill (one launch for Y0+Y1 contiguous region and hs)
// ---------------------------------------------------------------------------
__global__ void k_fill_sent2(float* __restrict__ a, int na4,
                             float* __restrict__ b, int nb4)
{
    int i = blockIdx.x * 256 + threadIdx.x;
    unsigned u = 0xFFFFFFFFu;
    float f = __builtin_bit_cast(float, u);
    float4 f4 = make_float4(f, f, f, f);
    if (i < na4) ((float4*)a)[i] = f4;
    else {
        int j = i - na4;
        if (j < nb4) ((float4*)b)[j] = f4;
    }
}

// ---------------------------------------------------------------------------
// p_term (unchanged)
// ---------------------------------------------------------------------------
__global__ __launch_bounds__(256) void k_pterm(
    const float* __restrict__ hs, const int* __restrict__ qids,
    const float* __restrict__ Wp, float* __restrict__ pterm)
{
    int b = blockIdx.y;
    int chunk = blockIdx.x;
    int tid = threadIdx.x;
    int qid = qids[b];
    __shared__ float hp[Hh];
    for (int i = tid; i < Hh; i += 256) hp[i] = hs[((long)(b * Tt + qid)) * Hh + i];
    __syncthreads();
    int w = tid >> 6, lane = tid & 63;
#pragma unroll
    for (int r = 0; r < 8; ++r) {
        int n = chunk * 32 + w * 8 + r;
        const float* wrow = &Wp[(long)n * Hh];
        float p = 0.f;
#pragma unroll
        for (int k0 = 0; k0 < 3; ++k0) {
            int k = lane * 4 + k0 * 256;
            float4 wv = *(const float4*)&wrow[k];
            float4 hv = *(const float4*)&hp[k];
            p += wv.x * hv.x + wv.y * hv.y + wv.z * hv.z + wv.w * hv.w;
        }
#pragma unroll
        for (int o = 32; o; o >>= 1) p += __shfl_down(p, o);
        if (lane == 0) pterm[b * Hh + n] = p;
    }
}

// ---------------------------------------------------------------------------
// Fused attention (unchanged)
// ---------------------------------------------------------------------------
__global__ __launch_bounds__(256) void k_attn(
    const float* __restrict__ hs, const float* __restrict__ A1, const float* __restrict__ A2,
    const float* __restrict__ v, const float* __restrict__ Wclf,
    float* __restrict__ a_mat, float* __restrict__ logits)
{
    int b = blockIdx.x >> 7, t = blockIdx.x & 127;
    int tid = threadIdx.x;
    long bt = (long)(b * Tt + t);

    __shared__ float a2r[Hh], vr[Hh], hsr[Hh], crow[Hh];
    __shared__ float sc[128], tmp[256], red2[2];

    for (int i = tid; i < Hh; i += 256) {
        a2r[i] = A2[bt * Hh + i];
        vr[i] = v[i];
        hsr[i] = hs[bt * Hh + i];
    }
    __syncthreads();

    {
        int sid = tid >> 1, half = tid & 1;
        float p = 0.f;
        const float* A1r = &A1[((long)(b * Tt + sid)) * Hh + half * 384];
        const float* a2h = &a2r[half * 384];
        const float* vh = &vr[half * 384];
        for (int k = 0; k < 384; k += 4) {
            float4 z = *(const float4*)&A1r[k];
            p += vh[k + 0] * fast_tanh(z.x + a2h[k + 0]);
            p += vh[k + 1] * fast_tanh(z.y + a2h[k + 1]);
            p += vh[k + 2] * fast_tanh(z.z + a2h[k + 2]);
            p += vh[k + 3] * fast_tanh(z.w + a2h[k + 3]);
        }
        tmp[tid] = p;
    }
    __syncthreads();
    if (tid < 128) sc[tid] = tmp[2 * tid] + tmp[2 * tid + 1];
    __syncthreads();

    if (tid < 64) {
        float m = fmaxf(sc[tid], sc[tid + 64]);
#pragma unroll
        for (int o = 32; o; o >>= 1) m = fmaxf(m, __shfl_down(m, o));
        if (tid == 0) red2[0] = m;
    }
    __syncthreads();
    float mx = red2[0];
    if (tid < 128) sc[tid] = __expf(sc[tid] - mx);
    __syncthreads();
    if (tid < 64) {
        float sm = sc[tid] + sc[tid + 64];
#pragma unroll
        for (int o = 32; o; o >>= 1) sm += __shfl_down(sm, o);
        if (tid == 0) red2[1] = sm;
    }
    __syncthreads();
    float inv = 1.f / red2[1];
    if (tid < 128) {
        sc[tid] *= inv;
        a_mat[bt * 128 + tid] = sc[tid];
    }
    __syncthreads();

    float c0 = 0.f, c1 = 0.f, c2 = 0.f;
    for (int s2 = 0; s2 < 128; ++s2) {
        float as = sc[s2];
        const float* hrow = &hs[((long)(b * Tt + s2)) * Hh];
        c0 = fmaf(as, hrow[tid], c0);
        c1 = fmaf(as, hrow[tid + 256], c1);
        c2 = fmaf(as, hrow[tid + 512], c2);
    }
    crow[tid] = c0; crow[tid + 256] = c1; crow[tid + 512] = c2;
    __syncthreads();

    for (int l = 0; l < Ll; ++l) {
        float p = 0.f;
        for (int h = tid; h < 2 * Hh; h += 256) {
            float u = (h < Hh) ? hsr[h] : crow[h - Hh];
            p = fmaf(u, Wclf[l * 2 * Hh + h], p);
        }
#pragma unroll
        for (int o = 32; o; o >>= 1) p += __shfl_down(p, o);
        if ((tid & 63) == 0) tmp[tid >> 6] = p;
        __syncthreads();
        if (tid == 0) logits[bt * Ll + l] = tmp[0] + tmp[1] + tmp[2] + tmp[3];
        __syncthreads();
    }
}

// ---------------------------------------------------------------------------
// a_t normalization (unchanged)
// ---------------------------------------------------------------------------
__global__ void k_norm(const float* __restrict__ a_mat, float* __restrict__ a_t)
{
    int b = blockIdx.x;
    int s = threadIdx.x;
    float sum = 0.f;
    for (int t = 0; t < Tt; ++t) sum += a_mat[((long)(b * Tt + t)) * 128 + s];
    __shared__ float pool[128];
    __shared__ float tot;
    pool[s] = sum;
    __syncthreads();
    if (s < 64) {
        float v2 = pool[s] + pool[s + 64];
#pragma unroll
        for (int o = 32; o; o >>= 1) v2 += __shfl_down(v2, o);
        if (s == 0) tot = v2;
    }
    __syncthreads();
    float tv = tot;
    a_t[b * 128 + s] = (tv != 0.f) ? pool[s] / tv : 0.f;
}

// ---------------------------------------------------------------------------
// Viterbi (unchanged)
// ---------------------------------------------------------------------------
__global__ void k_viterbi(const float* __restrict__ logits, const float* __restrict__ trans,
                          const float* __restrict__ start, const float* __restrict__ endw,
                          float* __restrict__ out)
{
    __shared__ float sc[2][72];
    __shared__ unsigned char ptrs[127][72];
    __shared__ unsigned char tags[8][128];
    int tid = threadIdx.x;
    int b = tid / 9, j = tid % 9;
    bool act = tid < 72;
    if (act) sc[0][b * 9 + j] = start[j] + logits[(b * Tt + 0) * Ll + j];
    __syncthreads();
    for (int t = 1; t < Tt; ++t) {
        int cur = t & 1, prv = cur ^ 1;
        if (act) {
            float best = -1e30f; int bi = 0;
#pragma unroll
            for (int i = 0; i < 9; ++i) {
                float vv = sc[prv][b * 9 + i] + trans[i * 9 + j];
                if (vv > best) { best = vv; bi = i; }
            }
            sc[cur][b * 9 + j] = best + logits[(b * Tt + t) * Ll + j];
            ptrs[t - 1][b * 9 + j] = (unsigned char)bi;
        }
        __syncthreads();
    }
    if (act && j == 0) {
        float best = -1e30f; int bj = 0;
#pragma unroll
        for (int jj = 0; jj < 9; ++jj) {
            float vv = sc[1][b * 9 + jj] + endw[jj];
            if (vv > best) { best = vv; bj = jj; }
        }
        int tg = bj;
        tags[b][127] = (unsigned char)tg;
        for (int t = 127; t >= 1; --t) {
            tg = ptrs[t - 1][b * 9 + tg];
            tags[b][t - 1] = (unsigned char)tg;
        }
    }
    __syncthreads();
    for (int i = tid; i < Bq * Tt * Ll; i += blockDim.x) {
        int l = i % 9;
        int btx = i / 9;
        int tt2 = btx % Tt;
        int bb = btx / Tt;
        out[i] = (tags[bb][tt2] == l) ? 10.f : -1.f;
    }
}

// ---------------------------------------------------------------------------
extern "C" void kernel_launch(void* const* d_in, const int* in_sizes, int n_in,
                              void* d_out, int out_size, void* d_ws, size_t ws_size,
                              hipStream_t stream)
{
    const float* embeds   = (const float*)d_in[0];
    const int*   qids     = (const int*)d_in[1];
    const float* w_ih_l0  = (const float*)d_in[2];
    const float* w_ih_rest= (const float*)d_in[3];
    const float* w_hh     = (const float*)d_in[4];
    const float* b_ih     = (const float*)d_in[5];
    const float* b_hh     = (const float*)d_in[6];
    const float* W_H      = (const float*)d_in[7];
    const float* W_p      = (const float*)d_in[8];
    const float* W_h      = (const float*)d_in[9];
    const float* vvec     = (const float*)d_in[10];
    const float* W_clf    = (const float*)d_in[11];
    const float* trans    = (const float*)d_in[12];
    const float* cstart   = (const float*)d_in[13];
    const float* cend     = (const float*)d_in[14];

    float* out = (float*)d_out;
    float* vit_out = out;                          // 8*128*9   = 9216
    float* hs      = out + 9216;                   // 8*128*768 = 786432
    float* a_t     = out + 9216 + 786432;          // 8*128     = 1024

    float* ws = (float*)d_ws;
    float* G      = ws;                  // 3145728 floats
    float* Y0     = ws + 3145728;        // 786432
    float* Y1     = Y0 + 786432;         // 786432 (contiguous with Y0)
    float* A1     = ws;                  // reuses G (dead after last lstm)
    float* A2     = A1 + 786432;
    float* pterm  = A2 + 786432;
    float* a_mat  = pterm + 6144;
    float* logits = a_mat + 131072;

    dim3 blk(256);
    const int nY4 = 2 * 786432 / 4;      // Y0+Y1 float4 count
    const int nH4 = 786432 / 4;          // hs float4 count
    const int fillgrid = (nY4 + nH4 + 255) / 256;

    // Sentinel pre-fill of the three exchange buffers (one launch).
    k_fill_sent2<<<dim3(fillgrid), blk, 0, stream>>>(Y0, nY4, hs, nH4);

    // ---- Layer 0 ----
    k_gemm<<<dim3(GATE / BN, 1024 / BM, 2), blk, 0, stream>>>(
        embeds, w_ih_l0, G, 1024, GATE, Ee,
        0L, (long)GATE * Ee, (long)1024 * GATE,
        b_ih, b_hh, (long)GATE, nullptr);
    k_lstm<<<dim3(64), blk, 0, stream>>>(G, w_hh, Y0);

    // ---- Layer 1 ----
    k_gemm<<<dim3(GATE / BN, 1024 / BM, 2), blk, 0, stream>>>(
        Y0, w_ih_rest, G, 1024, GATE, Hh,
        0L, (long)GATE * Hh, (long)1024 * GATE,
        b_ih + 2 * GATE, b_hh + 2 * GATE, (long)GATE, nullptr);
    k_lstm<<<dim3(64), blk, 0, stream>>>(G, w_hh + (long)2 * GATE * Ee, Y1);

    // ---- Layer 2 ----
    k_gemm<<<dim3(GATE / BN, 1024 / BM, 2), blk, 0, stream>>>(
        Y1, w_ih_rest + (long)2 * GATE * Hh, G, 1024, GATE, Hh,
        0L, (long)GATE * Hh, (long)1024 * GATE,
        b_ih + 4 * GATE, b_hh + 4 * GATE, (long)GATE, nullptr);
    k_lstm<<<dim3(64), blk, 0, stream>>>(G, w_hh + (long)4 * GATE * Ee, hs);

    // ---- Attention precompute ----
    k_pterm<<<dim3(24, 8), blk, 0, stream>>>(hs, qids, W_p, pterm);
    k_gemm<<<dim3(Hh / BN, 1024 / BM, 1), blk, 0, stream>>>(
        hs, W_H, A1, 1024, Hh, Hh, 0L, 0L, 0L, nullptr, nullptr, 0L, nullptr);
    k_gemm<<<dim3(Hh / BN, 1024 / BM, 1), blk, 0, stream>>>(
        hs, W_h, A2, 1024, Hh, Hh, 0L, 0L, 0L, nullptr, nullptr, 0L, pterm);

    // ---- Fused attention + logits ----
    k_attn<<<dim3(1024), blk, 0, stream>>>(hs, A1, A2, vvec, W_clf, a_mat, logits);

    // ---- Pooled attention norm -> a_t ----
    k_norm<<<dim3(8), dim3(128), 0, stream>>>(a_mat, a_t);

    // ---- Viterbi -> vit_logits ----
    k_viterbi<<<dim3(1), dim3(128), 0, stream>>>(logits, trans, cstart, cend, vit_out);
}